// Round 4
// baseline (342.071 us; speedup 1.0000x reference)
//
#include <hip/hip_runtime.h>

// GAT on line graph. Pipeline (round 4):
//   k_prevs : cast W->bf16; vs[8][64] = W^T @ att_{src,dst}
//   k_fused : heterogeneous grid —
//             proj blocks: MFMA h=x@W^T -> packed bf16 h2, exact fp32 a_src/a_dst
//             fill blocks: bucket 8 edges/thread by dst (cap 64) incl self loops
//   k_agg   : per-dst wave softmax + gather, software-pipelined 8-deep,
//             packed-f32 FMA consume
//   k_final : scatter-mean normalize + 64x64 linear

#define CAP 64

using frag16 = __attribute__((ext_vector_type(8))) short;  // 8 bf16
using f32x4  = __attribute__((ext_vector_type(4))) float;
using f32x2  = __attribute__((ext_vector_type(2))) float;

__device__ __forceinline__ float wave_reduce_sum(float v) {
#pragma unroll
  for (int off = 32; off > 0; off >>= 1) v += __shfl_xor(v, off, 64);
  return v;
}

// round-to-nearest f32 -> bf16 (cheap, <=0.5 ulp of bf16)
__device__ __forceinline__ unsigned short f2bf(float f) {
  union { float f; unsigned u; } v; v.f = f;
  return (unsigned short)((v.u + 0x8000u) >> 16);
}
__device__ __forceinline__ float bflo(unsigned u) {
  union { unsigned u; float f; } v; v.u = u << 16; return v.f;
}
__device__ __forceinline__ float bfhi(unsigned u) {
  union { unsigned u; float f; } v; v.u = u & 0xffff0000u; return v.f;
}

// ---------------- Pass 0: W cast + vs precompute ----------------
__global__ __launch_bounds__(256) void k_prevs(
    const float* __restrict__ W, const float* __restrict__ att_src,
    const float* __restrict__ att_dst, unsigned short* __restrict__ Wb,
    float* __restrict__ vs) {
  int t = blockIdx.x * 256 + threadIdx.x;    // 64 blocks -> 16384
  Wb[t] = f2bf(W[t]);
  if (blockIdx.x < 2) {
    int o = blockIdx.x * 256 + threadIdx.x;  // 0..511
    int j = o >> 6, c = o & 63;              // j: 0..3 src heads, 4..7 dst heads
    const float* att = (j < 4) ? att_src : att_dst;
    int hh = j & 3;
    float s = 0.f;
    for (int ch = 0; ch < 64; ++ch)
      s += W[(size_t)(hh * 64 + ch) * 64 + c] * att[hh * 64 + ch];
    vs[o] = s;
  }
}

// ---------------- Fused: projection blocks + fill blocks ----------------
__device__ __forceinline__ void proj_body(
    const float* __restrict__ x, const unsigned short* __restrict__ Wb,
    const float* __restrict__ vs, unsigned short* __restrict__ h2,
    float* __restrict__ a_src, float* __restrict__ a_dst, int bid,
    float* vsl /*LDS 512 floats*/) {
  const int t = threadIdx.x;
  if (t < 128) ((float4*)vsl)[t] = ((const float4*)vs)[t];
  __syncthreads();
  const int w = t >> 6, lane = t & 63, l15 = lane & 15, l4 = lane >> 4;
  const int e0 = bid * 64 + w * 16;
  const int row = e0 + l15;

  // Lane's 16 k-values of row: k = l4*8..+7 and 32+l4*8..+7
  const float4* xp = (const float4*)(x + (size_t)row * 64);
  float4 v0 = xp[l4 * 2], v1 = xp[l4 * 2 + 1];
  float4 v2 = xp[8 + l4 * 2], v3 = xp[8 + l4 * 2 + 1];
  float xa[16] = {v0.x, v0.y, v0.z, v0.w, v1.x, v1.y, v1.z, v1.w,
                  v2.x, v2.y, v2.z, v2.w, v3.x, v3.y, v3.z, v3.w};

  frag16 a0, a1;
#pragma unroll
  for (int i = 0; i < 8; ++i) {
    a0[i] = (short)f2bf(xa[i]);
    a1[i] = (short)f2bf(xa[8 + i]);
  }

  // Exact fp32 attention dots
  float pj[8];
#pragma unroll
  for (int j = 0; j < 8; ++j) {
    const float4* q = (const float4*)(vsl + j * 64 + l4 * 8);
    const float4* qb = (const float4*)(vsl + j * 64 + 32 + l4 * 8);
    float4 q0 = q[0], q1 = q[1], q2 = qb[0], q3 = qb[1];
    float s = xa[0] * q0.x + xa[1] * q0.y + xa[2] * q0.z + xa[3] * q0.w
            + xa[4] * q1.x + xa[5] * q1.y + xa[6] * q1.z + xa[7] * q1.w
            + xa[8] * q2.x + xa[9] * q2.y + xa[10] * q2.z + xa[11] * q2.w
            + xa[12] * q3.x + xa[13] * q3.y + xa[14] * q3.z + xa[15] * q3.w;
    s += __shfl_xor(s, 16, 64);
    s += __shfl_xor(s, 32, 64);
    pj[j] = s;
  }
  if (l4 == 0) {
    *(float4*)&a_src[(size_t)row * 4] = make_float4(pj[0], pj[1], pj[2], pj[3]);
    *(float4*)&a_dst[(size_t)row * 4] = make_float4(pj[4], pj[5], pj[6], pj[7]);
  }

  f32x4 acc[16];
#pragma unroll
  for (int nt = 0; nt < 16; ++nt) {
    const unsigned short* bp = Wb + (size_t)(nt * 16 + l15) * 64 + l4 * 8;
    frag16 b0 = *(const frag16*)(bp);
    frag16 b1 = *(const frag16*)(bp + 32);
    f32x4 c = {0.f, 0.f, 0.f, 0.f};
    c = __builtin_amdgcn_mfma_f32_16x16x32_bf16(a0, b0, c, 0, 0, 0);
    c = __builtin_amdgcn_mfma_f32_16x16x32_bf16(a1, b1, c, 0, 0, 0);
    acc[nt] = c;
  }

  // h2 row = 256 bf16, pos ch*4 + head. C map: row_local=l4*4+r, col=nt*16+l15
#pragma unroll
  for (int nt0 = 0; nt0 < 4; ++nt0) {
    int ch = nt0 * 16 + l15;
#pragma unroll
    for (int r = 0; r < 4; ++r) {
      int rrow = e0 + l4 * 4 + r;
      ushort4 vv;
      vv.x = f2bf(acc[nt0][r]);
      vv.y = f2bf(acc[nt0 + 4][r]);
      vv.z = f2bf(acc[nt0 + 8][r]);
      vv.w = f2bf(acc[nt0 + 12][r]);
      *(ushort4*)&h2[(size_t)rrow * 256 + ch * 4] = vv;
    }
  }
}

__device__ __forceinline__ void fill_body(
    const int* __restrict__ ei, int M, int E,
    int* __restrict__ cnt, int* __restrict__ csr, int bid) {
  const int Mtot = M + E;
  const int base = bid * 2048 + threadIdx.x;
  int mm[8], ss[8], dd[8];
#pragma unroll
  for (int i = 0; i < 8; ++i) {
    int m = base + i * 256;
    mm[i] = m;
    if (m < Mtot) {
      if (m < M) { ss[i] = ei[m]; dd[i] = ei[M + m]; }
      else       { ss[i] = m - M; dd[i] = m - M; }   // self loop
    }
  }
  int pos[8];
#pragma unroll
  for (int i = 0; i < 8; ++i)
    if (mm[i] < Mtot) pos[i] = atomicAdd(&cnt[dd[i]], 1);
#pragma unroll
  for (int i = 0; i < 8; ++i)
    if (mm[i] < Mtot && pos[i] < CAP) csr[(size_t)dd[i] * CAP + pos[i]] = ss[i];
}

__global__ __launch_bounds__(256, 4) void k_fused(
    const float* __restrict__ x, const unsigned short* __restrict__ Wb,
    const float* __restrict__ vs, unsigned short* __restrict__ h2,
    float* __restrict__ a_src, float* __restrict__ a_dst,
    const int* __restrict__ ei, int M, int E,
    int* __restrict__ cnt, int* __restrict__ csr,
    int nproj, int nfill) {
  __shared__ float vsl[512];
  const int bid = blockIdx.x;
  int npair = 2 * min(nproj, nfill);
  if (bid < npair) {
    if (bid & 1) proj_body(x, Wb, vs, h2, a_src, a_dst, bid >> 1, vsl);
    else         fill_body(ei, M, E, cnt, csr, bid >> 1);
  } else {
    int r = bid - npair;
    if (nfill > nproj) fill_body(ei, M, E, cnt, csr, nproj + r);
    else               proj_body(x, Wb, vs, h2, a_src, a_dst, nfill + r, vsl);
  }
}

// ---------------- Aggregation: softmax + pipelined gather ----------------
__global__ __launch_bounds__(256) void k_agg(
    const unsigned short* __restrict__ h2, const float4* __restrict__ a_src,
    const float4* __restrict__ a_dst, const int* __restrict__ cnt,
    const int* __restrict__ csr, const int* __restrict__ rows,
    const float* __restrict__ bias, float* __restrict__ agg,
    int* __restrict__ degc, int E) {
  __shared__ float4 alds[4 * 64];
  __shared__ int    olds[4 * 64];   // pre-scaled byte offsets: src*512
  const int w = threadIdx.x >> 6, lane = threadIdx.x & 63;
  const int e = blockIdx.x * 4 + w;          // E % 4 == 0

  int deg = cnt[e];
  if (deg > CAP) deg = CAP;
  float4 ad = a_dst[e];

  int src = 0;
  float ex0 = 0.f, ex1 = 0.f, ex2 = 0.f, ex3 = 0.f;
  if (lane < deg) {
    src = csr[(size_t)e * CAP + lane];
    float4 as = a_src[src];
    float l0 = as.x + ad.x; l0 = l0 > 0.f ? l0 : 0.2f * l0;
    float l1 = as.y + ad.y; l1 = l1 > 0.f ? l1 : 0.2f * l1;
    float l2 = as.z + ad.z; l2 = l2 > 0.f ? l2 : 0.2f * l2;
    float l3 = as.w + ad.w; l3 = l3 > 0.f ? l3 : 0.2f * l3;
    ex0 = __expf(l0); ex1 = __expf(l1); ex2 = __expf(l2); ex3 = __expf(l3);
  }
  float i0 = 1.f / (wave_reduce_sum(ex0) + 1e-16f);
  float i1 = 1.f / (wave_reduce_sum(ex1) + 1e-16f);
  float i2 = 1.f / (wave_reduce_sum(ex2) + 1e-16f);
  float i3 = 1.f / (wave_reduce_sum(ex3) + 1e-16f);

  alds[w * 64 + lane] = make_float4(ex0 * i0, ex1 * i1, ex2 * i2, ex3 * i3);
  olds[w * 64 + lane] = src << 9;            // src * 512 bytes
  __syncthreads();

  const char* hb = (const char*)h2 + (size_t)lane * 8;
  const int kb = w * 64;

#define LD(K) (*(const uint2*)(hb + (size_t)(unsigned)olds[kb + (K)]))
#define CONS1(K, V) { \
    float4 A_ = alds[kb + (K)]; \
    f32x2 al_; al_.x = A_.x; al_.y = A_.y; \
    f32x2 ah_; ah_.x = A_.z; ah_.y = A_.w; \
    f32x2 hl_; hl_.x = bflo((V).x); hl_.y = bfhi((V).x); \
    f32x2 hh_; hh_.x = bflo((V).y); hh_.y = bfhi((V).y); \
    acc01 += al_ * hl_; acc23 += ah_ * hh_; }

  f32x2 acc01 = {0.f, 0.f}, acc23 = {0.f, 0.f};
  int k = 0;
  if (deg >= 8) {
    uint2 p0 = LD(0), p1 = LD(1), p2 = LD(2), p3 = LD(3);
    for (; k + 8 <= deg; k += 4) {
      uint2 n0 = LD(k + 4), n1 = LD(k + 5), n2 = LD(k + 6), n3 = LD(k + 7);
      CONS1(k, p0) CONS1(k + 1, p1) CONS1(k + 2, p2) CONS1(k + 3, p3)
      p0 = n0; p1 = n1; p2 = n2; p3 = n3;
    }
    CONS1(k, p0) CONS1(k + 1, p1) CONS1(k + 2, p2) CONS1(k + 3, p3)
    k += 4;
  }
  for (; k < deg; ++k) {
    uint2 v = LD(k);
    CONS1(k, v)
  }
#undef LD
#undef CONS1

  float outc = 0.25f * (acc01.x + acc01.y + acc23.x + acc23.y) + bias[lane];
  int r = rows[e];
  atomicAdd(&agg[(size_t)r * 64 + lane], outc);
  if (lane == 0) atomicAdd(&degc[r], 1);
}

// ---------------- scatter-mean normalize + final linear ----------------
__global__ __launch_bounds__(256) void k_final(
    const float* __restrict__ agg, const int* __restrict__ degc,
    const float* __restrict__ wgt, const float* __restrict__ wb,
    float* __restrict__ out, int N) {
  __shared__ float wtt[64 * 65];
  const int t = threadIdx.x;
#pragma unroll
  for (int i = 0; i < 16; ++i) {
    int idx = t + i * 256;                       // idx = c*64 + k
    wtt[(idx & 63) * 65 + (idx >> 6)] = wgt[idx];
  }
  __syncthreads();
  const int w = t >> 6, lane = t & 63;
  int n = blockIdx.x * 4 + w;
  if (n >= N) return;
  int dg = degc[n];
  float av = dg > 0 ? agg[(size_t)n * 64 + lane] / (float)dg : 0.f;
  float o = 0.f;
#pragma unroll
  for (int k = 0; k < 64; ++k) {
    o += __shfl(av, k, 64) * wtt[k * 65 + lane];
  }
  out[(size_t)n * 64 + lane] = o + wb[lane];
}

extern "C" void kernel_launch(void* const* d_in, const int* in_sizes, int n_in,
                              void* d_out, int out_size, void* d_ws, size_t ws_size,
                              hipStream_t stream) {
  const float* x       = (const float*)d_in[0];
  const int*   ei      = (const int*)d_in[1];
  const int*   rows    = (const int*)d_in[2];
  const float* W       = (const float*)d_in[3];
  const float* att_src = (const float*)d_in[4];
  const float* att_dst = (const float*)d_in[5];
  const float* bias    = (const float*)d_in[6];
  const float* wgt     = (const float*)d_in[7];
  const float* wb      = (const float*)d_in[8];

  const int E = in_sizes[0] / 64;     // 131072
  const int M = in_sizes[1] / 2;      // 2097152
  const int N = out_size / 64;        // 16384

  char* p = (char*)d_ws;
  unsigned short* h2 = (unsigned short*)p;  p += (size_t)E * 256 * 2;  // 64MB
  int*   csr   = (int*)p;                   p += (size_t)E * CAP * 4;  // 32MB
  float* a_src = (float*)p;                 p += (size_t)E * 4 * 4;    // 2MB
  float* a_dst = (float*)p;                 p += (size_t)E * 4 * 4;    // 2MB
  int*   cnt   = (int*)p;                   p += (size_t)E * 4;        // 512KB
  float* agg   = (float*)p;                 p += (size_t)N * 64 * 4;   // 4MB
  int*   degc  = (int*)p;                   p += (size_t)N * 4;        // 64KB
  unsigned short* Wb = (unsigned short*)p;  p += 16384 * 2;            // 32KB
  float* vs    = (float*)p;                 p += 512 * 4;              // 2KB

  hipMemsetAsync(cnt, 0, (size_t)E * 4, stream);
  hipMemsetAsync(agg, 0, (size_t)N * 64 * 4 + (size_t)N * 4, stream);  // agg+degc

  k_prevs<<<64, 256, 0, stream>>>(W, att_src, att_dst, Wb, vs);

  const int Mtot = M + E;
  const int nproj = E / 64;                  // 2048
  const int nfill = (Mtot + 2047) / 2048;    // 1088
  k_fused<<<nproj + nfill, 256, 0, stream>>>(
      x, Wb, vs, h2, a_src, a_dst, ei, M, E, cnt, csr, nproj, nfill);

  k_agg<<<E / 4, 256, 0, stream>>>(
      h2, (const float4*)a_src, (const float4*)a_dst, cnt, csr,
      rows, bias, agg, degc, E);

  k_final<<<(N + 3) / 4, 256, 0, stream>>>(agg, degc, wgt, wb, (float*)d_out, N);
}

// Round 5
// 335.907 us; speedup vs baseline: 1.0183x; 1.0183x over previous
//
#include <hip/hip_runtime.h>

// GAT on line graph. Pipeline (round 5):
//   k_prevs : cast W->bf16; vs[8][64] = W^T @ att_{src,dst}
//   k_fused : SINGLE block type. Each block projects 64 rows (MFMA h=x@W^T ->
//             packed bf16 h2, exact fp32 a_src/a_dst) AND buckets 1088 edges
//             by dst (atomic latency hidden under the MFMA/a-dot phase).
//   k_agg   : per-dst wave softmax + gather. At the ~3.8 TB/s L2-miss-path
//             ceiling (FETCH 632 MB) -- do not touch.
//   k_final : scatter-mean normalize + 64x64 linear

#define CAP 64

using frag16 = __attribute__((ext_vector_type(8))) short;  // 8 bf16
using f32x4  = __attribute__((ext_vector_type(4))) float;
using f32x2  = __attribute__((ext_vector_type(2))) float;

__device__ __forceinline__ float wave_reduce_sum(float v) {
#pragma unroll
  for (int off = 32; off > 0; off >>= 1) v += __shfl_xor(v, off, 64);
  return v;
}

__device__ __forceinline__ unsigned short f2bf(float f) {
  union { float f; unsigned u; } v; v.f = f;
  return (unsigned short)((v.u + 0x8000u) >> 16);
}
__device__ __forceinline__ float bflo(unsigned u) {
  union { unsigned u; float f; } v; v.u = u << 16; return v.f;
}
__device__ __forceinline__ float bfhi(unsigned u) {
  union { unsigned u; float f; } v; v.u = u & 0xffff0000u; return v.f;
}

// ---------------- Pass 0: W cast + vs precompute ----------------
__global__ __launch_bounds__(256) void k_prevs(
    const float* __restrict__ W, const float* __restrict__ att_src,
    const float* __restrict__ att_dst, unsigned short* __restrict__ Wb,
    float* __restrict__ vs) {
  int t = blockIdx.x * 256 + threadIdx.x;    // 64 blocks -> 16384
  Wb[t] = f2bf(W[t]);
  if (blockIdx.x < 2) {
    int o = blockIdx.x * 256 + threadIdx.x;  // 0..511
    int j = o >> 6, c = o & 63;              // 0..3 src heads, 4..7 dst heads
    const float* att = (j < 4) ? att_src : att_dst;
    int hh = j & 3;
    float s = 0.f;
    for (int ch = 0; ch < 64; ++ch)
      s += W[(size_t)(hh * 64 + ch) * 64 + c] * att[hh * 64 + ch];
    vs[o] = s;
  }
}

// ---------------- Fused projection + edge bucketing ----------------
// 2048 blocks. Block bid: proj rows [bid*64, bid*64+64), edges
// [bid*1088, (bid+1)*1088) (Mtot = 2048*1088 exactly).
__global__ __launch_bounds__(256, 3) void k_fused(
    const float* __restrict__ x, const unsigned short* __restrict__ Wb,
    const float* __restrict__ vs, unsigned short* __restrict__ h2,
    float* __restrict__ a_src, float* __restrict__ a_dst,
    const int* __restrict__ ei, int M, int E,
    int* __restrict__ cnt, int* __restrict__ csr) {
  __shared__ float vsl[512];
  const int t = threadIdx.x;
  const int bid = blockIdx.x;

  // ---- fill phase A: issue edge-index loads (latency overlaps everything)
  const int ebase = bid * 1088;
  const int ne = (t < 64) ? 5 : 4;           // wave-uniform (wave 0 gets 5)
  int ss[5], dd[5];
#pragma unroll
  for (int i = 0; i < 5; ++i) {
    if (i < ne) {
      int m = ebase + i * 256 + t;           // < Mtot by construction
      if (m < M) { ss[i] = ei[m]; dd[i] = ei[M + m]; }
      else       { ss[i] = m - M; dd[i] = m - M; }   // self loop
    }
  }

  if (t < 128) ((float4*)vsl)[t] = ((const float4*)vs)[t];

  const int w = t >> 6, lane = t & 63, l15 = lane & 15, l4 = lane >> 4;
  const int e0 = bid * 64 + w * 16;
  const int row = e0 + l15;

  // Lane's 16 k-values of x row: k = l4*8..+7 and 32+l4*8..+7
  const float4* xp = (const float4*)(x + (size_t)row * 64);
  float4 v0 = xp[l4 * 2], v1 = xp[l4 * 2 + 1];
  float4 v2 = xp[8 + l4 * 2], v3 = xp[8 + l4 * 2 + 1];
  float xa[16] = {v0.x, v0.y, v0.z, v0.w, v1.x, v1.y, v1.z, v1.w,
                  v2.x, v2.y, v2.z, v2.w, v3.x, v3.y, v3.z, v3.w};

  // ---- fill phase B: fire cnt atomics (latency hidden under MFMA/a-dots)
  int pos[5];
#pragma unroll
  for (int i = 0; i < 5; ++i)
    if (i < ne) pos[i] = atomicAdd(&cnt[dd[i]], 1);

  frag16 a0, a1;
#pragma unroll
  for (int i = 0; i < 8; ++i) {
    a0[i] = (short)f2bf(xa[i]);
    a1[i] = (short)f2bf(xa[8 + i]);
  }

  __syncthreads();   // vsl ready

  // Exact fp32 attention dots: a_{src,dst}[row][h] = x[row] . vs[j]
  float pj[8];
#pragma unroll
  for (int j = 0; j < 8; ++j) {
    const float4* q = (const float4*)(vsl + j * 64 + l4 * 8);
    const float4* qb = (const float4*)(vsl + j * 64 + 32 + l4 * 8);
    float4 q0 = q[0], q1 = q[1], q2 = qb[0], q3 = qb[1];
    float s = xa[0] * q0.x + xa[1] * q0.y + xa[2] * q0.z + xa[3] * q0.w
            + xa[4] * q1.x + xa[5] * q1.y + xa[6] * q1.z + xa[7] * q1.w
            + xa[8] * q2.x + xa[9] * q2.y + xa[10] * q2.z + xa[11] * q2.w
            + xa[12] * q3.x + xa[13] * q3.y + xa[14] * q3.z + xa[15] * q3.w;
    s += __shfl_xor(s, 16, 64);
    s += __shfl_xor(s, 32, 64);
    pj[j] = s;
  }
  if (l4 == 0) {
    *(float4*)&a_src[(size_t)row * 4] = make_float4(pj[0], pj[1], pj[2], pj[3]);
    *(float4*)&a_dst[(size_t)row * 4] = make_float4(pj[4], pj[5], pj[6], pj[7]);
  }

  // MFMA: 16 col-tiles of 16 (heads*ch = 256 outputs)
  f32x4 acc[16];
#pragma unroll
  for (int nt = 0; nt < 16; ++nt) {
    const unsigned short* bp = Wb + (size_t)(nt * 16 + l15) * 64 + l4 * 8;
    frag16 b0 = *(const frag16*)(bp);
    frag16 b1 = *(const frag16*)(bp + 32);
    f32x4 c = {0.f, 0.f, 0.f, 0.f};
    c = __builtin_amdgcn_mfma_f32_16x16x32_bf16(a0, b0, c, 0, 0, 0);
    c = __builtin_amdgcn_mfma_f32_16x16x32_bf16(a1, b1, c, 0, 0, 0);
    acc[nt] = c;
  }

  // h2 row = 256 bf16, pos ch*4 + head. C map: row_local=l4*4+r, col=nt*16+l15
#pragma unroll
  for (int nt0 = 0; nt0 < 4; ++nt0) {
    int ch = nt0 * 16 + l15;
#pragma unroll
    for (int r = 0; r < 4; ++r) {
      int rrow = e0 + l4 * 4 + r;
      ushort4 vv;
      vv.x = f2bf(acc[nt0][r]);
      vv.y = f2bf(acc[nt0 + 4][r]);
      vv.z = f2bf(acc[nt0 + 8][r]);
      vv.w = f2bf(acc[nt0 + 12][r]);
      *(ushort4*)&h2[(size_t)rrow * 256 + ch * 4] = vv;
    }
  }

  // ---- fill phase C: drain csr stores (pos has long returned by now)
#pragma unroll
  for (int i = 0; i < 5; ++i)
    if (i < ne && pos[i] < CAP) csr[(size_t)dd[i] * CAP + pos[i]] = ss[i];
}

// ---------------- Aggregation: softmax + pipelined gather ----------------
__global__ __launch_bounds__(256) void k_agg(
    const unsigned short* __restrict__ h2, const float4* __restrict__ a_src,
    const float4* __restrict__ a_dst, const int* __restrict__ cnt,
    const int* __restrict__ csr, const int* __restrict__ rows,
    const float* __restrict__ bias, float* __restrict__ agg,
    int* __restrict__ degc, int E) {
  __shared__ float4 alds[4 * 64];
  __shared__ int    olds[4 * 64];   // pre-scaled byte offsets: src*512
  const int w = threadIdx.x >> 6, lane = threadIdx.x & 63;
  const int e = blockIdx.x * 4 + w;          // E % 4 == 0

  int deg = cnt[e];
  if (deg > CAP) deg = CAP;
  float4 ad = a_dst[e];

  int src = 0;
  float ex0 = 0.f, ex1 = 0.f, ex2 = 0.f, ex3 = 0.f;
  if (lane < deg) {
    src = csr[(size_t)e * CAP + lane];
    float4 as = a_src[src];
    float l0 = as.x + ad.x; l0 = l0 > 0.f ? l0 : 0.2f * l0;
    float l1 = as.y + ad.y; l1 = l1 > 0.f ? l1 : 0.2f * l1;
    float l2 = as.z + ad.z; l2 = l2 > 0.f ? l2 : 0.2f * l2;
    float l3 = as.w + ad.w; l3 = l3 > 0.f ? l3 : 0.2f * l3;
    ex0 = __expf(l0); ex1 = __expf(l1); ex2 = __expf(l2); ex3 = __expf(l3);
  }
  float i0 = 1.f / (wave_reduce_sum(ex0) + 1e-16f);
  float i1 = 1.f / (wave_reduce_sum(ex1) + 1e-16f);
  float i2 = 1.f / (wave_reduce_sum(ex2) + 1e-16f);
  float i3 = 1.f / (wave_reduce_sum(ex3) + 1e-16f);

  alds[w * 64 + lane] = make_float4(ex0 * i0, ex1 * i1, ex2 * i2, ex3 * i3);
  olds[w * 64 + lane] = src << 9;            // src * 512 bytes
  __syncthreads();

  const char* hb = (const char*)h2 + (size_t)lane * 8;
  const int kb = w * 64;

#define LD(K) (*(const uint2*)(hb + (size_t)(unsigned)olds[kb + (K)]))
#define CONS1(K, V) { \
    float4 A_ = alds[kb + (K)]; \
    f32x2 al_; al_.x = A_.x; al_.y = A_.y; \
    f32x2 ah_; ah_.x = A_.z; ah_.y = A_.w; \
    f32x2 hl_; hl_.x = bflo((V).x); hl_.y = bfhi((V).x); \
    f32x2 hh_; hh_.x = bflo((V).y); hh_.y = bfhi((V).y); \
    acc01 += al_ * hl_; acc23 += ah_ * hh_; }

  f32x2 acc01 = {0.f, 0.f}, acc23 = {0.f, 0.f};
  int k = 0;
  if (deg >= 8) {
    uint2 p0 = LD(0), p1 = LD(1), p2 = LD(2), p3 = LD(3);
    for (; k + 8 <= deg; k += 4) {
      uint2 n0 = LD(k + 4), n1 = LD(k + 5), n2 = LD(k + 6), n3 = LD(k + 7);
      CONS1(k, p0) CONS1(k + 1, p1) CONS1(k + 2, p2) CONS1(k + 3, p3)
      p0 = n0; p1 = n1; p2 = n2; p3 = n3;
    }
    CONS1(k, p0) CONS1(k + 1, p1) CONS1(k + 2, p2) CONS1(k + 3, p3)
    k += 4;
  }
  for (; k < deg; ++k) {
    uint2 v = LD(k);
    CONS1(k, v)
  }
#undef LD
#undef CONS1

  float outc = 0.25f * (acc01.x + acc01.y + acc23.x + acc23.y) + bias[lane];
  int r = rows[e];
  atomicAdd(&agg[(size_t)r * 64 + lane], outc);
  if (lane == 0) atomicAdd(&degc[r], 1);
}

// ---------------- scatter-mean normalize + final linear ----------------
__global__ __launch_bounds__(256) void k_final(
    const float* __restrict__ agg, const int* __restrict__ degc,
    const float* __restrict__ wgt, const float* __restrict__ wb,
    float* __restrict__ out, int N) {
  __shared__ float wtt[64 * 65];
  const int t = threadIdx.x;
#pragma unroll
  for (int i = 0; i < 16; ++i) {
    int idx = t + i * 256;                       // idx = c*64 + k
    wtt[(idx & 63) * 65 + (idx >> 6)] = wgt[idx];
  }
  __syncthreads();
  const int w = t >> 6, lane = t & 63;
  int n = blockIdx.x * 4 + w;
  if (n >= N) return;
  int dg = degc[n];
  float av = dg > 0 ? agg[(size_t)n * 64 + lane] / (float)dg : 0.f;
  float o = 0.f;
#pragma unroll
  for (int k = 0; k < 64; ++k) {
    o += __shfl(av, k, 64) * wtt[k * 65 + lane];
  }
  out[(size_t)n * 64 + lane] = o + wb[lane];
}

extern "C" void kernel_launch(void* const* d_in, const int* in_sizes, int n_in,
                              void* d_out, int out_size, void* d_ws, size_t ws_size,
                              hipStream_t stream) {
  const float* x       = (const float*)d_in[0];
  const int*   ei      = (const int*)d_in[1];
  const int*   rows    = (const int*)d_in[2];
  const float* W       = (const float*)d_in[3];
  const float* att_src = (const float*)d_in[4];
  const float* att_dst = (const float*)d_in[5];
  const float* bias    = (const float*)d_in[6];
  const float* wgt     = (const float*)d_in[7];
  const float* wb      = (const float*)d_in[8];

  const int E = in_sizes[0] / 64;     // 131072
  const int M = in_sizes[1] / 2;      // 2097152
  const int N = out_size / 64;        // 16384

  char* p = (char*)d_ws;
  unsigned short* h2 = (unsigned short*)p;  p += (size_t)E * 256 * 2;  // 64MB
  int*   csr   = (int*)p;                   p += (size_t)E * CAP * 4;  // 32MB
  float* a_src = (float*)p;                 p += (size_t)E * 4 * 4;    // 2MB
  float* a_dst = (float*)p;                 p += (size_t)E * 4 * 4;    // 2MB
  int*   cnt   = (int*)p;                   p += (size_t)E * 4;        // 512KB
  float* agg   = (float*)p;                 p += (size_t)N * 64 * 4;   // 4MB
  int*   degc  = (int*)p;                   p += (size_t)N * 4;        // 64KB
  unsigned short* Wb = (unsigned short*)p;  p += 16384 * 2;            // 32KB
  float* vs    = (float*)p;                 p += 512 * 4;              // 2KB

  hipMemsetAsync(cnt, 0, (size_t)E * 4, stream);
  hipMemsetAsync(agg, 0, (size_t)N * 64 * 4 + (size_t)N * 4, stream);  // agg+degc

  k_prevs<<<64, 256, 0, stream>>>(W, att_src, att_dst, Wb, vs);

  // Mtot = M + E = 2228224 = 2048 * 1088 exactly; 2048 = E/64 proj blocks.
  k_fused<<<E / 64, 256, 0, stream>>>(
      x, Wb, vs, h2, a_src, a_dst, ei, M, E, cnt, csr);

  k_agg<<<E / 4, 256, 0, stream>>>(
      h2, (const float4*)a_src, (const float4*)a_dst, cnt, csr,
      rows, bias, agg, degc, E);

  k_final<<<(N + 3) / 4, 256, 0, stream>>>(agg, degc, wgt, wb, (float*)d_out, N);
}

// Round 6
// 325.054 us; speedup vs baseline: 1.0523x; 1.0334x over previous
//
#include <hip/hip_runtime.h>

// GAT on line graph. Pipeline (round 6):
//   k_prevs : cast W->bf16; vs[8][64] = W^T @ att_{src,dst}
//   k_fused : heterogeneous grid (r3 structure): proj blocks (MFMA h=x@W^T ->
//             packed bf16 h2, exact fp32 a_src/a_dst) interleaved with fill
//             blocks (4 edges/thread). cnt counters PADDED to one per 64B
//             cache line (kills per-line atomic queueing across 8 XCDs).
//   k_agg   : per-dst wave softmax + pipelined gather. At ~3.8 TB/s L2-fill
//             ceiling (FETCH 632 MB) -- do not touch.
//   k_final : scatter-mean normalize + 64x64 linear

#define CAP 64
#define CSTRIDE 16   // ints per counter: one counter per 64B line

using frag16 = __attribute__((ext_vector_type(8))) short;  // 8 bf16
using f32x4  = __attribute__((ext_vector_type(4))) float;
using f32x2  = __attribute__((ext_vector_type(2))) float;

__device__ __forceinline__ float wave_reduce_sum(float v) {
#pragma unroll
  for (int off = 32; off > 0; off >>= 1) v += __shfl_xor(v, off, 64);
  return v;
}

__device__ __forceinline__ unsigned short f2bf(float f) {
  union { float f; unsigned u; } v; v.f = f;
  return (unsigned short)((v.u + 0x8000u) >> 16);
}
__device__ __forceinline__ float bflo(unsigned u) {
  union { unsigned u; float f; } v; v.u = u << 16; return v.f;
}
__device__ __forceinline__ float bfhi(unsigned u) {
  union { unsigned u; float f; } v; v.u = u & 0xffff0000u; return v.f;
}

// ---------------- Pass 0: W cast + vs precompute ----------------
__global__ __launch_bounds__(256) void k_prevs(
    const float* __restrict__ W, const float* __restrict__ att_src,
    const float* __restrict__ att_dst, unsigned short* __restrict__ Wb,
    float* __restrict__ vs) {
  int t = blockIdx.x * 256 + threadIdx.x;    // 64 blocks -> 16384
  Wb[t] = f2bf(W[t]);
  if (blockIdx.x < 2) {
    int o = blockIdx.x * 256 + threadIdx.x;  // 0..511
    int j = o >> 6, c = o & 63;              // 0..3 src heads, 4..7 dst heads
    const float* att = (j < 4) ? att_src : att_dst;
    int hh = j & 3;
    float s = 0.f;
    for (int ch = 0; ch < 64; ++ch)
      s += W[(size_t)(hh * 64 + ch) * 64 + c] * att[hh * 64 + ch];
    vs[o] = s;
  }
}

// ---------------- Fused: projection blocks + fill blocks ----------------
__device__ __forceinline__ void proj_body(
    const float* __restrict__ x, const unsigned short* __restrict__ Wb,
    const float* __restrict__ vs, unsigned short* __restrict__ h2,
    float* __restrict__ a_src, float* __restrict__ a_dst, int bid,
    float* vsl /*LDS 512 floats*/) {
  const int t = threadIdx.x;
  if (t < 128) ((float4*)vsl)[t] = ((const float4*)vs)[t];
  __syncthreads();
  const int w = t >> 6, lane = t & 63, l15 = lane & 15, l4 = lane >> 4;
  const int e0 = bid * 64 + w * 16;
  const int row = e0 + l15;

  // Lane's 16 k-values of x row: k = l4*8..+7 and 32+l4*8..+7
  const float4* xp = (const float4*)(x + (size_t)row * 64);
  float4 v0 = xp[l4 * 2], v1 = xp[l4 * 2 + 1];
  float4 v2 = xp[8 + l4 * 2], v3 = xp[8 + l4 * 2 + 1];
  float xa[16] = {v0.x, v0.y, v0.z, v0.w, v1.x, v1.y, v1.z, v1.w,
                  v2.x, v2.y, v2.z, v2.w, v3.x, v3.y, v3.z, v3.w};

  frag16 a0, a1;
#pragma unroll
  for (int i = 0; i < 8; ++i) {
    a0[i] = (short)f2bf(xa[i]);
    a1[i] = (short)f2bf(xa[8 + i]);
  }

  // Exact fp32 attention dots
  float pj[8];
#pragma unroll
  for (int j = 0; j < 8; ++j) {
    const float4* q = (const float4*)(vsl + j * 64 + l4 * 8);
    const float4* qb = (const float4*)(vsl + j * 64 + 32 + l4 * 8);
    float4 q0 = q[0], q1 = q[1], q2 = qb[0], q3 = qb[1];
    float s = xa[0] * q0.x + xa[1] * q0.y + xa[2] * q0.z + xa[3] * q0.w
            + xa[4] * q1.x + xa[5] * q1.y + xa[6] * q1.z + xa[7] * q1.w
            + xa[8] * q2.x + xa[9] * q2.y + xa[10] * q2.z + xa[11] * q2.w
            + xa[12] * q3.x + xa[13] * q3.y + xa[14] * q3.z + xa[15] * q3.w;
    s += __shfl_xor(s, 16, 64);
    s += __shfl_xor(s, 32, 64);
    pj[j] = s;
  }
  if (l4 == 0) {
    *(float4*)&a_src[(size_t)row * 4] = make_float4(pj[0], pj[1], pj[2], pj[3]);
    *(float4*)&a_dst[(size_t)row * 4] = make_float4(pj[4], pj[5], pj[6], pj[7]);
  }

  f32x4 acc[16];
#pragma unroll
  for (int nt = 0; nt < 16; ++nt) {
    const unsigned short* bp = Wb + (size_t)(nt * 16 + l15) * 64 + l4 * 8;
    frag16 b0 = *(const frag16*)(bp);
    frag16 b1 = *(const frag16*)(bp + 32);
    f32x4 c = {0.f, 0.f, 0.f, 0.f};
    c = __builtin_amdgcn_mfma_f32_16x16x32_bf16(a0, b0, c, 0, 0, 0);
    c = __builtin_amdgcn_mfma_f32_16x16x32_bf16(a1, b1, c, 0, 0, 0);
    acc[nt] = c;
  }

  // h2 row = 256 bf16, pos ch*4 + head. C map: row_local=l4*4+r, col=nt*16+l15
#pragma unroll
  for (int nt0 = 0; nt0 < 4; ++nt0) {
    int ch = nt0 * 16 + l15;
#pragma unroll
    for (int r = 0; r < 4; ++r) {
      int rrow = e0 + l4 * 4 + r;
      ushort4 vv;
      vv.x = f2bf(acc[nt0][r]);
      vv.y = f2bf(acc[nt0 + 4][r]);
      vv.z = f2bf(acc[nt0 + 8][r]);
      vv.w = f2bf(acc[nt0 + 12][r]);
      *(ushort4*)&h2[(size_t)rrow * 256 + ch * 4] = vv;
    }
  }
}

__device__ __forceinline__ void fill_body(
    const int* __restrict__ ei, int M, int E,
    int* __restrict__ cnt, int* __restrict__ csr, int bid) {
  const int Mtot = M + E;
  const int base = bid * 1024 + threadIdx.x;
  int mm[4], ss[4], dd[4];
#pragma unroll
  for (int i = 0; i < 4; ++i) {
    int m = base + i * 256;
    mm[i] = m;
    if (m < Mtot) {
      if (m < M) { ss[i] = ei[m]; dd[i] = ei[M + m]; }
      else       { ss[i] = m - M; dd[i] = m - M; }   // self loop
    }
  }
  int pos[4];
#pragma unroll
  for (int i = 0; i < 4; ++i)
    if (mm[i] < Mtot) pos[i] = atomicAdd(&cnt[dd[i] * CSTRIDE], 1);
#pragma unroll
  for (int i = 0; i < 4; ++i)
    if (mm[i] < Mtot && pos[i] < CAP) csr[(size_t)dd[i] * CAP + pos[i]] = ss[i];
}

__global__ __launch_bounds__(256, 4) void k_fused(
    const float* __restrict__ x, const unsigned short* __restrict__ Wb,
    const float* __restrict__ vs, unsigned short* __restrict__ h2,
    float* __restrict__ a_src, float* __restrict__ a_dst,
    const int* __restrict__ ei, int M, int E,
    int* __restrict__ cnt, int* __restrict__ csr,
    int nproj, int nfill) {
  __shared__ float vsl[512];
  const int bid = blockIdx.x;
  int npair = 2 * min(nproj, nfill);
  if (bid < npair) {
    if (bid & 1) proj_body(x, Wb, vs, h2, a_src, a_dst, bid >> 1, vsl);
    else         fill_body(ei, M, E, cnt, csr, bid >> 1);
  } else {
    int r = bid - npair;
    if (nfill > nproj) fill_body(ei, M, E, cnt, csr, nproj + r);
    else               proj_body(x, Wb, vs, h2, a_src, a_dst, nfill + r, vsl);
  }
}

// ---------------- Aggregation: softmax + pipelined gather ----------------
__global__ __launch_bounds__(256) void k_agg(
    const unsigned short* __restrict__ h2, const float4* __restrict__ a_src,
    const float4* __restrict__ a_dst, const int* __restrict__ cnt,
    const int* __restrict__ csr, const int* __restrict__ rows,
    const float* __restrict__ bias, float* __restrict__ agg,
    int* __restrict__ degc, int E) {
  __shared__ float4 alds[4 * 64];
  __shared__ int    olds[4 * 64];   // pre-scaled byte offsets: src*512
  const int w = threadIdx.x >> 6, lane = threadIdx.x & 63;
  const int e = blockIdx.x * 4 + w;          // E % 4 == 0

  int deg = cnt[(size_t)e * CSTRIDE];
  if (deg > CAP) deg = CAP;
  float4 ad = a_dst[e];

  int src = 0;
  float ex0 = 0.f, ex1 = 0.f, ex2 = 0.f, ex3 = 0.f;
  if (lane < deg) {
    src = csr[(size_t)e * CAP + lane];
    float4 as = a_src[src];
    float l0 = as.x + ad.x; l0 = l0 > 0.f ? l0 : 0.2f * l0;
    float l1 = as.y + ad.y; l1 = l1 > 0.f ? l1 : 0.2f * l1;
    float l2 = as.z + ad.z; l2 = l2 > 0.f ? l2 : 0.2f * l2;
    float l3 = as.w + ad.w; l3 = l3 > 0.f ? l3 : 0.2f * l3;
    ex0 = __expf(l0); ex1 = __expf(l1); ex2 = __expf(l2); ex3 = __expf(l3);
  }
  float i0 = 1.f / (wave_reduce_sum(ex0) + 1e-16f);
  float i1 = 1.f / (wave_reduce_sum(ex1) + 1e-16f);
  float i2 = 1.f / (wave_reduce_sum(ex2) + 1e-16f);
  float i3 = 1.f / (wave_reduce_sum(ex3) + 1e-16f);

  alds[w * 64 + lane] = make_float4(ex0 * i0, ex1 * i1, ex2 * i2, ex3 * i3);
  olds[w * 64 + lane] = src << 9;            // src * 512 bytes
  __syncthreads();

  const char* hb = (const char*)h2 + (size_t)lane * 8;
  const int kb = w * 64;

#define LD(K) (*(const uint2*)(hb + (size_t)(unsigned)olds[kb + (K)]))
#define CONS1(K, V) { \
    float4 A_ = alds[kb + (K)]; \
    f32x2 al_; al_.x = A_.x; al_.y = A_.y; \
    f32x2 ah_; ah_.x = A_.z; ah_.y = A_.w; \
    f32x2 hl_; hl_.x = bflo((V).x); hl_.y = bfhi((V).x); \
    f32x2 hh_; hh_.x = bflo((V).y); hh_.y = bfhi((V).y); \
    acc01 += al_ * hl_; acc23 += ah_ * hh_; }

  f32x2 acc01 = {0.f, 0.f}, acc23 = {0.f, 0.f};
  int k = 0;
  if (deg >= 8) {
    uint2 p0 = LD(0), p1 = LD(1), p2 = LD(2), p3 = LD(3);
    for (; k + 8 <= deg; k += 4) {
      uint2 n0 = LD(k + 4), n1 = LD(k + 5), n2 = LD(k + 6), n3 = LD(k + 7);
      CONS1(k, p0) CONS1(k + 1, p1) CONS1(k + 2, p2) CONS1(k + 3, p3)
      p0 = n0; p1 = n1; p2 = n2; p3 = n3;
    }
    CONS1(k, p0) CONS1(k + 1, p1) CONS1(k + 2, p2) CONS1(k + 3, p3)
    k += 4;
  }
  for (; k < deg; ++k) {
    uint2 v = LD(k);
    CONS1(k, v)
  }
#undef LD
#undef CONS1

  float outc = 0.25f * (acc01.x + acc01.y + acc23.x + acc23.y) + bias[lane];
  int r = rows[e];
  atomicAdd(&agg[(size_t)r * 64 + lane], outc);
  if (lane == 0) atomicAdd(&degc[r], 1);
}

// ---------------- scatter-mean normalize + final linear ----------------
__global__ __launch_bounds__(256) void k_final(
    const float* __restrict__ agg, const int* __restrict__ degc,
    const float* __restrict__ wgt, const float* __restrict__ wb,
    float* __restrict__ out, int N) {
  __shared__ float wtt[64 * 65];
  const int t = threadIdx.x;
#pragma unroll
  for (int i = 0; i < 16; ++i) {
    int idx = t + i * 256;                       // idx = c*64 + k
    wtt[(idx & 63) * 65 + (idx >> 6)] = wgt[idx];
  }
  __syncthreads();
  const int w = t >> 6, lane = t & 63;
  int n = blockIdx.x * 4 + w;
  if (n >= N) return;
  int dg = degc[n];
  float av = dg > 0 ? agg[(size_t)n * 64 + lane] / (float)dg : 0.f;
  float o = 0.f;
#pragma unroll
  for (int k = 0; k < 64; ++k) {
    o += __shfl(av, k, 64) * wtt[k * 65 + lane];
  }
  out[(size_t)n * 64 + lane] = o + wb[lane];
}

extern "C" void kernel_launch(void* const* d_in, const int* in_sizes, int n_in,
                              void* d_out, int out_size, void* d_ws, size_t ws_size,
                              hipStream_t stream) {
  const float* x       = (const float*)d_in[0];
  const int*   ei      = (const int*)d_in[1];
  const int*   rows    = (const int*)d_in[2];
  const float* W       = (const float*)d_in[3];
  const float* att_src = (const float*)d_in[4];
  const float* att_dst = (const float*)d_in[5];
  const float* bias    = (const float*)d_in[6];
  const float* wgt     = (const float*)d_in[7];
  const float* wb      = (const float*)d_in[8];

  const int E = in_sizes[0] / 64;     // 131072
  const int M = in_sizes[1] / 2;      // 2097152
  const int N = out_size / 64;        // 16384

  char* p = (char*)d_ws;
  unsigned short* h2 = (unsigned short*)p;  p += (size_t)E * 256 * 2;        // 64MB
  int*   csr   = (int*)p;                   p += (size_t)E * CAP * 4;        // 32MB
  float* a_src = (float*)p;                 p += (size_t)E * 4 * 4;          // 2MB
  float* a_dst = (float*)p;                 p += (size_t)E * 4 * 4;          // 2MB
  // cnt, agg, degc contiguous -> single memset
  int*   cnt   = (int*)p;                   p += (size_t)E * CSTRIDE * 4;    // 8MB
  float* agg   = (float*)p;                 p += (size_t)N * 64 * 4;         // 4MB
  int*   degc  = (int*)p;                   p += (size_t)N * 4;              // 64KB
  unsigned short* Wb = (unsigned short*)p;  p += 16384 * 2;                  // 32KB
  float* vs    = (float*)p;                 p += 512 * 4;                    // 2KB

  hipMemsetAsync(cnt, 0,
                 (size_t)E * CSTRIDE * 4 + (size_t)N * 64 * 4 + (size_t)N * 4,
                 stream);

  k_prevs<<<64, 256, 0, stream>>>(W, att_src, att_dst, Wb, vs);

  const int Mtot = M + E;
  const int nproj = E / 64;                  // 2048
  const int nfill = (Mtot + 1023) / 1024;    // 2176
  k_fused<<<nproj + nfill, 256, 0, stream>>>(
      x, Wb, vs, h2, a_src, a_dst, ei, M, E, cnt, csr, nproj, nfill);

  k_agg<<<E / 4, 256, 0, stream>>>(
      h2, (const float4*)a_src, (const float4*)a_dst, cnt, csr,
      rows, bias, agg, degc, E);

  k_final<<<(N + 3) / 4, 256, 0, stream>>>(agg, degc, wgt, wb, (float*)d_out, N);
}

// Round 7
// 306.523 us; speedup vs baseline: 1.1160x; 1.0605x over previous
//
#include <hip/hip_runtime.h>

// GAT on line graph. Pipeline (round 7):
//   k_prevs : vs[8][64] = W^T@att ; Btr[c][kap]=0.25*W[(kap>>6)*64+c][kap&63] bf16
//   k_fused : heterogeneous grid: cast blocks (x->bf16 xb + exact fp32
//             a_src/a_dst) paired with fill blocks (CSR bucket, 4 edges/thr).
//   k_agg   : per-dst wave softmax; alpha-weighted gather of x rows (128B bf16,
//             4x less than h rows) into z[h][64]; per-block MFMA epilogue
//             out = z @ Btr^T (+bias), atomic scatter into agg[rows[e]].
//   k_final : scatter-mean normalize + 64x64 linear

#define CAP 64

using frag16 = __attribute__((ext_vector_type(8))) short;  // 8 bf16
using f32x4  = __attribute__((ext_vector_type(4))) float;

__device__ __forceinline__ float wave_reduce_sum(float v) {
#pragma unroll
  for (int off = 32; off > 0; off >>= 1) v += __shfl_xor(v, off, 64);
  return v;
}

__device__ __forceinline__ unsigned short f2bf(float f) {
  union { float f; unsigned u; } v; v.f = f;
  return (unsigned short)((v.u + 0x8000u) >> 16);
}
__device__ __forceinline__ float bflo(unsigned u) {
  union { unsigned u; float f; } v; v.u = u << 16; return v.f;
}
__device__ __forceinline__ float bfhi(unsigned u) {
  union { unsigned u; float f; } v; v.u = u & 0xffff0000u; return v.f;
}

// ---------------- Pass 0: vs + Btr precompute ----------------
__global__ __launch_bounds__(256) void k_prevs(
    const float* __restrict__ W, const float* __restrict__ att_src,
    const float* __restrict__ att_dst, unsigned short* __restrict__ Btr,
    float* __restrict__ vs) {
  int t = blockIdx.x * 256 + threadIdx.x;    // 64 blocks -> 16384
  {
    int c = t >> 8, kap = t & 255;           // Btr[c][kap] = 0.25*W[h*64+c][k]
    int h = kap >> 6, k = kap & 63;
    Btr[t] = f2bf(0.25f * W[(size_t)(h * 64 + c) * 64 + k]);
  }
  if (blockIdx.x < 2) {
    int o = blockIdx.x * 256 + threadIdx.x;  // 0..511
    int j = o >> 6, c = o & 63;              // 0..3 src heads, 4..7 dst heads
    const float* att = (j < 4) ? att_src : att_dst;
    int hh = j & 3;
    float s = 0.f;
    for (int ch = 0; ch < 64; ++ch)
      s += W[(size_t)(hh * 64 + ch) * 64 + c] * att[hh * 64 + ch];
    vs[o] = s;
  }
}

// ---------------- Fused: cast blocks + fill blocks ----------------
__device__ __forceinline__ void cast_body(
    const float* __restrict__ x, const float* __restrict__ vs,
    unsigned short* __restrict__ xb, float* __restrict__ a_src,
    float* __restrict__ a_dst, int bid, float* vsl) {
  const int t = threadIdx.x;
  if (t < 128) ((float4*)vsl)[t] = ((const float4*)vs)[t];
  __syncthreads();
  const int w = t >> 6, lane = t & 63, l15 = lane & 15, l4 = lane >> 4;
  const int row = bid * 64 + w * 16 + l15;

  // lane's 16 dims: l4*16 .. +15
  const float4* xp = (const float4*)(x + (size_t)row * 64 + l4 * 16);
  float4 v0 = xp[0], v1 = xp[1], v2 = xp[2], v3 = xp[3];
  float xa[16] = {v0.x, v0.y, v0.z, v0.w, v1.x, v1.y, v1.z, v1.w,
                  v2.x, v2.y, v2.z, v2.w, v3.x, v3.y, v3.z, v3.w};

  // pack bf16 pairs (even dim = lo, odd = hi) -> uint4 (32B)
  uint4 pk;
  pk.x = (unsigned)f2bf(xa[0])  | ((unsigned)f2bf(xa[1])  << 16);
  pk.y = (unsigned)f2bf(xa[2])  | ((unsigned)f2bf(xa[3])  << 16);
  pk.z = (unsigned)f2bf(xa[4])  | ((unsigned)f2bf(xa[5])  << 16);
  pk.w = (unsigned)f2bf(xa[6])  | ((unsigned)f2bf(xa[7])  << 16);
  uint4 pk2;
  pk2.x = (unsigned)f2bf(xa[8])  | ((unsigned)f2bf(xa[9])  << 16);
  pk2.y = (unsigned)f2bf(xa[10]) | ((unsigned)f2bf(xa[11]) << 16);
  pk2.z = (unsigned)f2bf(xa[12]) | ((unsigned)f2bf(xa[13]) << 16);
  pk2.w = (unsigned)f2bf(xa[14]) | ((unsigned)f2bf(xa[15]) << 16);
  uint2* dst = (uint2*)(xb + (size_t)row * 64 + l4 * 16);
  dst[0] = make_uint2(pk.x, pk.y);
  dst[1] = make_uint2(pk.z, pk.w);
  dst[2] = make_uint2(pk2.x, pk2.y);
  dst[3] = make_uint2(pk2.z, pk2.w);

  // exact fp32 attention dots (partial over 16 dims, reduce across l4)
  float pj[8];
#pragma unroll
  for (int j = 0; j < 8; ++j) {
    const float4* q = (const float4*)(vsl + j * 64 + l4 * 16);
    float4 q0 = q[0], q1 = q[1], q2 = q[2], q3 = q[3];
    float s = xa[0] * q0.x + xa[1] * q0.y + xa[2] * q0.z + xa[3] * q0.w
            + xa[4] * q1.x + xa[5] * q1.y + xa[6] * q1.z + xa[7] * q1.w
            + xa[8] * q2.x + xa[9] * q2.y + xa[10] * q2.z + xa[11] * q2.w
            + xa[12] * q3.x + xa[13] * q3.y + xa[14] * q3.z + xa[15] * q3.w;
    s += __shfl_xor(s, 16, 64);
    s += __shfl_xor(s, 32, 64);
    pj[j] = s;
  }
  if (l4 == 0) {
    *(float4*)&a_src[(size_t)row * 4] = make_float4(pj[0], pj[1], pj[2], pj[3]);
    *(float4*)&a_dst[(size_t)row * 4] = make_float4(pj[4], pj[5], pj[6], pj[7]);
  }
}

__device__ __forceinline__ void fill_body(
    const int* __restrict__ ei, int M, int E,
    int* __restrict__ cnt, int* __restrict__ csr, int bid) {
  const int Mtot = M + E;
  const int base = bid * 1024 + threadIdx.x;
  int mm[4], ss[4], dd[4];
#pragma unroll
  for (int i = 0; i < 4; ++i) {
    int m = base + i * 256;
    mm[i] = m;
    if (m < Mtot) {
      if (m < M) { ss[i] = ei[m]; dd[i] = ei[M + m]; }
      else       { ss[i] = m - M; dd[i] = m - M; }   // self loop
    }
  }
  int pos[4];
#pragma unroll
  for (int i = 0; i < 4; ++i)
    if (mm[i] < Mtot) pos[i] = atomicAdd(&cnt[dd[i]], 1);
#pragma unroll
  for (int i = 0; i < 4; ++i)
    if (mm[i] < Mtot && pos[i] < CAP) csr[(size_t)dd[i] * CAP + pos[i]] = ss[i];
}

__global__ __launch_bounds__(256, 4) void k_fused(
    const float* __restrict__ x, const float* __restrict__ vs,
    unsigned short* __restrict__ xb,
    float* __restrict__ a_src, float* __restrict__ a_dst,
    const int* __restrict__ ei, int M, int E,
    int* __restrict__ cnt, int* __restrict__ csr,
    int ncast, int nfill) {
  __shared__ float vsl[512];
  const int bid = blockIdx.x;
  int npair = 2 * min(ncast, nfill);
  if (bid < npair) {
    if (bid & 1) cast_body(x, vs, xb, a_src, a_dst, bid >> 1, vsl);
    else         fill_body(ei, M, E, cnt, csr, bid >> 1);
  } else {
    int r = bid - npair;
    if (nfill > ncast) fill_body(ei, M, E, cnt, csr, ncast + r);
    else               cast_body(x, vs, xb, a_src, a_dst, ncast + r, vsl);
  }
}

// ---------------- Aggregation: softmax + x-gather + MFMA epilogue ----------
__global__ __launch_bounds__(256) void k_agg(
    const unsigned short* __restrict__ xb, const float4* __restrict__ a_src,
    const float4* __restrict__ a_dst, const int* __restrict__ cnt,
    const int* __restrict__ csr, const int* __restrict__ rows,
    const unsigned short* __restrict__ Btr, const float* __restrict__ bias,
    float* __restrict__ agg, int* __restrict__ degc, int E) {
  __shared__ float4 alds[4 * 64];
  __shared__ int    olds[4 * 64];        // pre-scaled byte offsets: src*128
  __shared__ float  zl[4][2][256];       // [wave][half][kappa=h*64+k]  8KB
  const int w = threadIdx.x >> 6, lane = threadIdx.x & 63;
  const int e = blockIdx.x * 4 + w;      // grid exactly E/4

  int deg = cnt[e];
  if (deg > CAP) deg = CAP;
  float4 ad = a_dst[e];

  int src = 0;
  float ex0 = 0.f, ex1 = 0.f, ex2 = 0.f, ex3 = 0.f;
  if (lane < deg) {
    src = csr[(size_t)e * CAP + lane];
    float4 as = a_src[src];
    float l0 = as.x + ad.x; l0 = l0 > 0.f ? l0 : 0.2f * l0;
    float l1 = as.y + ad.y; l1 = l1 > 0.f ? l1 : 0.2f * l1;
    float l2 = as.z + ad.z; l2 = l2 > 0.f ? l2 : 0.2f * l2;
    float l3 = as.w + ad.w; l3 = l3 > 0.f ? l3 : 0.2f * l3;
    ex0 = __expf(l0); ex1 = __expf(l1); ex2 = __expf(l2); ex3 = __expf(l3);
  }
  float i0 = 1.f / (wave_reduce_sum(ex0) + 1e-16f);
  float i1 = 1.f / (wave_reduce_sum(ex1) + 1e-16f);
  float i2 = 1.f / (wave_reduce_sum(ex2) + 1e-16f);
  float i3 = 1.f / (wave_reduce_sum(ex3) + 1e-16f);

  alds[w * 64 + lane] = make_float4(ex0 * i0, ex1 * i1, ex2 * i2, ex3 * i3);
  olds[w * 64 + lane] = src << 7;        // x row = 128 bytes
  __syncthreads();

  // phase 2: z[h][2 dims] accumulation; half-wave j handles neighbor 2i+j
  const int j = lane >> 5, d2 = lane & 31;
  const char* xbase = (const char*)xb + d2 * 4;
  const int kb = w * 64;
  float z0 = 0.f, z1 = 0.f, z2 = 0.f, z3 = 0.f;
  float z4 = 0.f, z5 = 0.f, z6 = 0.f, z7 = 0.f;
  const int npair_ = (deg + 1) >> 1;
#pragma unroll 4
  for (int i = 0; i < npair_; ++i) {
    int k = 2 * i + j;                       // k <= 63; alpha=0 beyond deg
    float4 A = alds[kb + k];
    unsigned v = *(const unsigned*)(xbase + (size_t)(unsigned)olds[kb + k]);
    float xl = bflo(v), xh = bfhi(v);
    z0 = fmaf(A.x, xl, z0); z1 = fmaf(A.x, xh, z1);
    z2 = fmaf(A.y, xl, z2); z3 = fmaf(A.y, xh, z3);
    z4 = fmaf(A.z, xl, z4); z5 = fmaf(A.z, xh, z5);
    z6 = fmaf(A.w, xl, z6); z7 = fmaf(A.w, xh, z7);
  }

  // phase 3: stage z into LDS: kappa = h*64 + 2*d2 (+0/1)
  *(float2*)&zl[w][j][0 * 64 + 2 * d2] = make_float2(z0, z1);
  *(float2*)&zl[w][j][1 * 64 + 2 * d2] = make_float2(z2, z3);
  *(float2*)&zl[w][j][2 * 64 + 2 * d2] = make_float2(z4, z5);
  *(float2*)&zl[w][j][3 * 64 + 2 * d2] = make_float2(z6, z7);
  __syncthreads();

  // epilogue: out[4 dst][64 c] = z @ Btr^T ; wave w -> col tile w (c=w*16+l15)
  const int l15 = lane & 15, l4 = lane >> 4;
  const int drow = l15 & 3;              // A row content: dst index (dups ok)
  const unsigned short* bp = Btr + (size_t)(w * 16 + l15) * 256 + l4 * 8;
  const float* z0p = &zl[drow][0][l4 * 8];
  const float* z1p = &zl[drow][1][l4 * 8];
  f32x4 acc = {0.f, 0.f, 0.f, 0.f};
#pragma unroll
  for (int kk = 0; kk < 8; ++kk) {
    frag16 af, bfg;
#pragma unroll
    for (int q = 0; q < 8; ++q)
      af[q] = (short)f2bf(z0p[kk * 32 + q] + z1p[kk * 32 + q]);
    bfg = *(const frag16*)(bp + kk * 32);
    acc = __builtin_amdgcn_mfma_f32_16x16x32_bf16(af, bfg, acc, 0, 0, 0);
  }
  // C map: row = l4*4 + reg, col = l15 -> rows 0..3 live in lanes l4==0
  if (l4 == 0) {
    int ccol = w * 16 + l15;
    float bs = bias[ccol];
#pragma unroll
    for (int r = 0; r < 4; ++r) {
      int ee = blockIdx.x * 4 + r;
      atomicAdd(&agg[(size_t)rows[ee] * 64 + ccol], acc[r] + bs);
    }
  }
  if (lane == 0) atomicAdd(&degc[rows[e]], 1);
}

// ---------------- scatter-mean normalize + final linear ----------------
__global__ __launch_bounds__(256) void k_final(
    const float* __restrict__ agg, const int* __restrict__ degc,
    const float* __restrict__ wgt, const float* __restrict__ wb,
    float* __restrict__ out, int N) {
  __shared__ float wtt[64 * 65];
  const int t = threadIdx.x;
#pragma unroll
  for (int i = 0; i < 16; ++i) {
    int idx = t + i * 256;                       // idx = c*64 + k
    wtt[(idx & 63) * 65 + (idx >> 6)] = wgt[idx];
  }
  __syncthreads();
  const int w = t >> 6, lane = t & 63;
  int n = blockIdx.x * 4 + w;
  if (n >= N) return;
  int dg = degc[n];
  float av = dg > 0 ? agg[(size_t)n * 64 + lane] / (float)dg : 0.f;
  float o = 0.f;
#pragma unroll
  for (int k = 0; k < 64; ++k) {
    o += __shfl(av, k, 64) * wtt[k * 65 + lane];
  }
  out[(size_t)n * 64 + lane] = o + wb[lane];
}

extern "C" void kernel_launch(void* const* d_in, const int* in_sizes, int n_in,
                              void* d_out, int out_size, void* d_ws, size_t ws_size,
                              hipStream_t stream) {
  const float* x       = (const float*)d_in[0];
  const int*   ei      = (const int*)d_in[1];
  const int*   rows    = (const int*)d_in[2];
  const float* W       = (const float*)d_in[3];
  const float* att_src = (const float*)d_in[4];
  const float* att_dst = (const float*)d_in[5];
  const float* bias    = (const float*)d_in[6];
  const float* wgt     = (const float*)d_in[7];
  const float* wb      = (const float*)d_in[8];

  const int E = in_sizes[0] / 64;     // 131072
  const int M = in_sizes[1] / 2;      // 2097152
  const int N = out_size / 64;        // 16384

  char* p = (char*)d_ws;
  unsigned short* xb = (unsigned short*)p;  p += (size_t)E * 64 * 2;   // 16MB
  int*   csr   = (int*)p;                   p += (size_t)E * CAP * 4;  // 32MB
  float* a_src = (float*)p;                 p += (size_t)E * 4 * 4;    // 2MB
  float* a_dst = (float*)p;                 p += (size_t)E * 4 * 4;    // 2MB
  // cnt, agg, degc contiguous -> single memset
  int*   cnt   = (int*)p;                   p += (size_t)E * 4;        // 512KB
  float* agg   = (float*)p;                 p += (size_t)N * 64 * 4;   // 4MB
  int*   degc  = (int*)p;                   p += (size_t)N * 4;        // 64KB
  unsigned short* Btr = (unsigned short*)p; p += 64 * 256 * 2;         // 32KB
  float* vs    = (float*)p;                 p += 512 * 4;              // 2KB

  hipMemsetAsync(cnt, 0,
                 (size_t)E * 4 + (size_t)N * 64 * 4 + (size_t)N * 4, stream);

  k_prevs<<<64, 256, 0, stream>>>(W, att_src, att_dst, Btr, vs);

  const int Mtot = M + E;
  const int ncast = E / 64;                  // 2048
  const int nfill = (Mtot + 1023) / 1024;    // 2176
  k_fused<<<ncast + nfill, 256, 0, stream>>>(
      x, vs, xb, a_src, a_dst, ei, M, E, cnt, csr, ncast, nfill);

  k_agg<<<E / 4, 256, 0, stream>>>(
      xb, (const float4*)a_src, (const float4*)a_dst, cnt, csr,
      rows, Btr, bias, agg, degc, E);

  k_final<<<(N + 3) / 4, 256, 0, stream>>>(agg, degc, wgt, wb, (float*)d_out, N);
}

// Round 8
// 299.305 us; speedup vs baseline: 1.1429x; 1.0241x over previous
//
#include <hip/hip_runtime.h>
#include <hip/hip_bf16.h>

// GAT on line graph. Pipeline (round 8):
//   k_prevs : vs[8][64] = W^T@att ; Btr[c][kap]=0.25*W[(kap>>6)*64+c][kap&63] bf16
//   k_fused : heterogeneous grid: cast blocks (x->bf16 xb + exact fp32
//             a_src/a_dst) paired with fill blocks (CSR bucket, 4 edges/thr).
//   k_agg   : per-dst wave softmax; alpha-weighted gather of x rows (128B bf16)
//             into z (f32x2 pk-FMA), half-wave reduce in-register, stage in
//             conflict-free zl[4][260], MFMA epilogue out = z @ Btr^T (+bias),
//             atomic scatter into agg[rows[e]].
//   k_final : scatter-mean normalize + 64x64 linear

#define CAP 64
#define ZST 260   // zl stride: mod32=4 -> 2-way max on epilogue reads (free)

using frag16 = __attribute__((ext_vector_type(8))) short;  // 8 bf16
using f32x4  = __attribute__((ext_vector_type(4))) float;
using f32x2  = __attribute__((ext_vector_type(2))) float;

__device__ __forceinline__ float wave_reduce_sum(float v) {
#pragma unroll
  for (int off = 32; off > 0; off >>= 1) v += __shfl_xor(v, off, 64);
  return v;
}

__device__ __forceinline__ unsigned short f2bf(float f) {
  union { float f; unsigned u; } v; v.f = f;
  return (unsigned short)((v.u + 0x8000u) >> 16);
}
__device__ __forceinline__ float bflo(unsigned u) {
  union { unsigned u; float f; } v; v.u = u << 16; return v.f;
}
__device__ __forceinline__ float bfhi(unsigned u) {
  union { unsigned u; float f; } v; v.u = u & 0xffff0000u; return v.f;
}
__device__ __forceinline__ unsigned pkbf(float lo, float hi) {
  union { __hip_bfloat162 b; unsigned u; } v;
  v.b = __float22bfloat162_rn(make_float2(lo, hi));   // v_cvt_pk_bf16_f32
  return v.u;
}

// ---------------- Pass 0: vs + Btr precompute ----------------
__global__ __launch_bounds__(256) void k_prevs(
    const float* __restrict__ W, const float* __restrict__ att_src,
    const float* __restrict__ att_dst, unsigned short* __restrict__ Btr,
    float* __restrict__ vs) {
  int t = blockIdx.x * 256 + threadIdx.x;    // 64 blocks -> 16384
  {
    int c = t >> 8, kap = t & 255;           // Btr[c][kap] = 0.25*W[h*64+c][k]
    int h = kap >> 6, k = kap & 63;
    Btr[t] = f2bf(0.25f * W[(size_t)(h * 64 + c) * 64 + k]);
  }
  if (blockIdx.x < 2) {
    int o = blockIdx.x * 256 + threadIdx.x;  // 0..511
    int j = o >> 6, c = o & 63;              // 0..3 src heads, 4..7 dst heads
    const float* att = (j < 4) ? att_src : att_dst;
    int hh = j & 3;
    float s = 0.f;
    for (int ch = 0; ch < 64; ++ch)
      s += W[(size_t)(hh * 64 + ch) * 64 + c] * att[hh * 64 + ch];
    vs[o] = s;
  }
}

// ---------------- Fused: cast blocks + fill blocks ----------------
__device__ __forceinline__ void cast_body(
    const float* __restrict__ x, const float* __restrict__ vs,
    unsigned short* __restrict__ xb, float* __restrict__ a_src,
    float* __restrict__ a_dst, int bid, float* vsl) {
  const int t = threadIdx.x;
  if (t < 128) ((float4*)vsl)[t] = ((const float4*)vs)[t];
  __syncthreads();
  const int w = t >> 6, lane = t & 63, l15 = lane & 15, l4 = lane >> 4;
  const int row = bid * 64 + w * 16 + l15;

  // lane's 16 dims: l4*16 .. +15
  const float4* xp = (const float4*)(x + (size_t)row * 64 + l4 * 16);
  float4 v0 = xp[0], v1 = xp[1], v2 = xp[2], v3 = xp[3];
  float xa[16] = {v0.x, v0.y, v0.z, v0.w, v1.x, v1.y, v1.z, v1.w,
                  v2.x, v2.y, v2.z, v2.w, v3.x, v3.y, v3.z, v3.w};

  // pack bf16 pairs (even dim = lo, odd = hi)
  uint2* dst = (uint2*)(xb + (size_t)row * 64 + l4 * 16);
  dst[0] = make_uint2(pkbf(xa[0], xa[1]),  pkbf(xa[2], xa[3]));
  dst[1] = make_uint2(pkbf(xa[4], xa[5]),  pkbf(xa[6], xa[7]));
  dst[2] = make_uint2(pkbf(xa[8], xa[9]),  pkbf(xa[10], xa[11]));
  dst[3] = make_uint2(pkbf(xa[12], xa[13]), pkbf(xa[14], xa[15]));

  // exact fp32 attention dots (partial over 16 dims, reduce across l4)
  float pj[8];
#pragma unroll
  for (int j = 0; j < 8; ++j) {
    const float4* q = (const float4*)(vsl + j * 64 + l4 * 16);
    float4 q0 = q[0], q1 = q[1], q2 = q[2], q3 = q[3];
    float s = xa[0] * q0.x + xa[1] * q0.y + xa[2] * q0.z + xa[3] * q0.w
            + xa[4] * q1.x + xa[5] * q1.y + xa[6] * q1.z + xa[7] * q1.w
            + xa[8] * q2.x + xa[9] * q2.y + xa[10] * q2.z + xa[11] * q2.w
            + xa[12] * q3.x + xa[13] * q3.y + xa[14] * q3.z + xa[15] * q3.w;
    s += __shfl_xor(s, 16, 64);
    s += __shfl_xor(s, 32, 64);
    pj[j] = s;
  }
  if (l4 == 0) {
    *(float4*)&a_src[(size_t)row * 4] = make_float4(pj[0], pj[1], pj[2], pj[3]);
    *(float4*)&a_dst[(size_t)row * 4] = make_float4(pj[4], pj[5], pj[6], pj[7]);
  }
}

__device__ __forceinline__ void fill_body(
    const int* __restrict__ ei, int M, int E,
    int* __restrict__ cnt, int* __restrict__ csr, int bid) {
  const int Mtot = M + E;
  const int base = bid * 1024 + threadIdx.x;
  int mm[4], ss[4], dd[4];
#pragma unroll
  for (int i = 0; i < 4; ++i) {
    int m = base + i * 256;
    mm[i] = m;
    if (m < Mtot) {
      if (m < M) { ss[i] = ei[m]; dd[i] = ei[M + m]; }
      else       { ss[i] = m - M; dd[i] = m - M; }   // self loop
    }
  }
  int pos[4];
#pragma unroll
  for (int i = 0; i < 4; ++i)
    if (mm[i] < Mtot) pos[i] = atomicAdd(&cnt[dd[i]], 1);
#pragma unroll
  for (int i = 0; i < 4; ++i)
    if (mm[i] < Mtot && pos[i] < CAP) csr[(size_t)dd[i] * CAP + pos[i]] = ss[i];
}

__global__ __launch_bounds__(256, 4) void k_fused(
    const float* __restrict__ x, const float* __restrict__ vs,
    unsigned short* __restrict__ xb,
    float* __restrict__ a_src, float* __restrict__ a_dst,
    const int* __restrict__ ei, int M, int E,
    int* __restrict__ cnt, int* __restrict__ csr,
    int ncast, int nfill) {
  __shared__ float vsl[512];
  const int bid = blockIdx.x;
  int npair = 2 * min(ncast, nfill);
  if (bid < npair) {
    if (bid & 1) cast_body(x, vs, xb, a_src, a_dst, bid >> 1, vsl);
    else         fill_body(ei, M, E, cnt, csr, bid >> 1);
  } else {
    int r = bid - npair;
    if (nfill > ncast) fill_body(ei, M, E, cnt, csr, ncast + r);
    else               cast_body(x, vs, xb, a_src, a_dst, ncast + r, vsl);
  }
}

// ---------------- Aggregation: softmax + x-gather + MFMA epilogue ----------
__global__ __launch_bounds__(256) void k_agg(
    const unsigned short* __restrict__ xb, const float4* __restrict__ a_src,
    const float4* __restrict__ a_dst, const int* __restrict__ cnt,
    const int* __restrict__ csr, const int* __restrict__ rows,
    const unsigned short* __restrict__ Btr, const float* __restrict__ bias,
    float* __restrict__ agg, int* __restrict__ degc, int E) {
  __shared__ float4 alds[4 * 64];
  __shared__ int    olds[4 * 64];        // pre-scaled byte offsets: src*128
  __shared__ float  zl[4 * ZST];         // [dst wave][kappa], stride 260
  const int w = threadIdx.x >> 6, lane = threadIdx.x & 63;
  const int e = blockIdx.x * 4 + w;      // grid exactly E/4

  int deg = cnt[e];
  if (deg > CAP) deg = CAP;
  float4 ad = a_dst[e];

  int src = 0;
  float ex0 = 0.f, ex1 = 0.f, ex2 = 0.f, ex3 = 0.f;
  if (lane < deg) {
    src = csr[(size_t)e * CAP + lane];
    float4 as = a_src[src];
    float l0 = as.x + ad.x; l0 = l0 > 0.f ? l0 : 0.2f * l0;
    float l1 = as.y + ad.y; l1 = l1 > 0.f ? l1 : 0.2f * l1;
    float l2 = as.z + ad.z; l2 = l2 > 0.f ? l2 : 0.2f * l2;
    float l3 = as.w + ad.w; l3 = l3 > 0.f ? l3 : 0.2f * l3;
    ex0 = __expf(l0); ex1 = __expf(l1); ex2 = __expf(l2); ex3 = __expf(l3);
  }
  float i0 = 1.f / (wave_reduce_sum(ex0) + 1e-16f);
  float i1 = 1.f / (wave_reduce_sum(ex1) + 1e-16f);
  float i2 = 1.f / (wave_reduce_sum(ex2) + 1e-16f);
  float i3 = 1.f / (wave_reduce_sum(ex3) + 1e-16f);

  alds[w * 64 + lane] = make_float4(ex0 * i0, ex1 * i1, ex2 * i2, ex3 * i3);
  olds[w * 64 + lane] = src << 7;        // x row = 128 bytes
  __syncthreads();

  // phase 2: packed z accumulation; half-wave j handles neighbor 2i+j.
  // lane (j,d2) accumulates z[h][2*d2 .. 2*d2+1] for h=0..3 (f32x2 each).
  const int j = lane >> 5, d2 = lane & 31;
  const char* xbase = (const char*)xb + d2 * 4;
  const int kb = w * 64;
  f32x2 zz0 = {0.f, 0.f}, zz1 = {0.f, 0.f}, zz2 = {0.f, 0.f}, zz3 = {0.f, 0.f};
  const int npair_ = (deg + 1) >> 1;
  for (int i = 0; i < npair_; ++i) {
    int k = 2 * i + j;                       // k <= 63; alpha=0 beyond deg
    float4 A = alds[kb + k];
    unsigned v = *(const unsigned*)(xbase + (size_t)(unsigned)olds[kb + k]);
    f32x2 xv; xv.x = bflo(v); xv.y = bfhi(v);
    f32x2 a0 = {A.x, A.x}, a1 = {A.y, A.y}, a2 = {A.z, A.z}, a3 = {A.w, A.w};
    zz0 += a0 * xv; zz1 += a1 * xv; zz2 += a2 * xv; zz3 += a3 * xv;
  }
  // reduce the two halves in-register (each half holds the other parity's k)
  zz0.x += __shfl_xor(zz0.x, 32, 64); zz0.y += __shfl_xor(zz0.y, 32, 64);
  zz1.x += __shfl_xor(zz1.x, 32, 64); zz1.y += __shfl_xor(zz1.y, 32, 64);
  zz2.x += __shfl_xor(zz2.x, 32, 64); zz2.y += __shfl_xor(zz2.y, 32, 64);
  zz3.x += __shfl_xor(zz3.x, 32, 64); zz3.y += __shfl_xor(zz3.y, 32, 64);

  // phase 3: stage z (j==0 half only; both halves identical now)
  if (j == 0) {
    float* zw = &zl[w * ZST + 2 * d2];
    *(float2*)&zw[0 * 64] = make_float2(zz0.x, zz0.y);
    *(float2*)&zw[1 * 64] = make_float2(zz1.x, zz1.y);
    *(float2*)&zw[2 * 64] = make_float2(zz2.x, zz2.y);
    *(float2*)&zw[3 * 64] = make_float2(zz3.x, zz3.y);
  }
  __syncthreads();

  // epilogue: out[4 dst][64 c] = z @ Btr^T ; wave w -> col tile w (c=w*16+l15)
  const int l15 = lane & 15, l4 = lane >> 4;
  const int drow = l15 & 3;              // A row content: dst index (dups ok)
  const unsigned short* bp = Btr + (size_t)(w * 16 + l15) * 256 + l4 * 8;
  const float* zp = &zl[drow * ZST + l4 * 8];
  f32x4 acc = {0.f, 0.f, 0.f, 0.f};
#pragma unroll
  for (int kk = 0; kk < 8; ++kk) {
    const float4* z4p = (const float4*)(zp + kk * 32);
    float4 za = z4p[0], zb = z4p[1];
    frag16 af;
    unsigned* au = (unsigned*)&af;
    au[0] = pkbf(za.x, za.y);
    au[1] = pkbf(za.z, za.w);
    au[2] = pkbf(zb.x, zb.y);
    au[3] = pkbf(zb.z, zb.w);
    frag16 bfg = *(const frag16*)(bp + kk * 32);
    acc = __builtin_amdgcn_mfma_f32_16x16x32_bf16(af, bfg, acc, 0, 0, 0);
  }
  // C map: row = l4*4 + reg, col = l15 -> rows 0..3 live in lanes l4==0
  if (l4 == 0) {
    int ccol = w * 16 + l15;
    float bs = bias[ccol];
#pragma unroll
    for (int r = 0; r < 4; ++r) {
      int ee = blockIdx.x * 4 + r;
      atomicAdd(&agg[(size_t)rows[ee] * 64 + ccol], acc[r] + bs);
    }
  }
  if (lane == 0) atomicAdd(&degc[rows[e]], 1);
}

// ---------------- scatter-mean normalize + final linear ----------------
__global__ __launch_bounds__(256) void k_final(
    const float* __restrict__ agg, const int* __restrict__ degc,
    const float* __restrict__ wgt, const float* __restrict__ wb,
    float* __restrict__ out, int N) {
  __shared__ float wtt[64 * 65];
  const int t = threadIdx.x;
#pragma unroll
  for (int i = 0; i < 16; ++i) {
    int idx = t + i * 256;                       // idx = c*64 + k
    wtt[(idx & 63) * 65 + (idx >> 6)] = wgt[idx];
  }
  __syncthreads();
  const int w = t >> 6, lane = t & 63;
  int n = blockIdx.x * 4 + w;
  if (n >= N) return;
  int dg = degc[n];
  float av = dg > 0 ? agg[(size_t)n * 64 + lane] / (float)dg : 0.f;
  float o = 0.f;
#pragma unroll
  for (int k = 0; k < 64; ++k) {
    o += __shfl(av, k, 64) * wtt[k * 65 + lane];
  }
  out[(size_t)n * 64 + lane] = o + wb[lane];
}

extern "C" void kernel_launch(void* const* d_in, const int* in_sizes, int n_in,
                              void* d_out, int out_size, void* d_ws, size_t ws_size,
                              hipStream_t stream) {
  const float* x       = (const float*)d_in[0];
  const int*   ei      = (const int*)d_in[1];
  const int*   rows    = (const int*)d_in[2];
  const float* W       = (const float*)d_in[3];
  const float* att_src = (const float*)d_in[4];
  const float* att_dst = (const float*)d_in[5];
  const float* bias    = (const float*)d_in[6];
  const float* wgt     = (const float*)d_in[7];
  const float* wb      = (const float*)d_in[8];

  const int E = in_sizes[0] / 64;     // 131072
  const int M = in_sizes[1] / 2;      // 2097152
  const int N = out_size / 64;        // 16384

  char* p = (char*)d_ws;
  unsigned short* xb = (unsigned short*)p;  p += (size_t)E * 64 * 2;   // 16MB
  int*   csr   = (int*)p;                   p += (size_t)E * CAP * 4;  // 32MB
  float* a_src = (float*)p;                 p += (size_t)E * 4 * 4;    // 2MB
  float* a_dst = (float*)p;                 p += (size_t)E * 4 * 4;    // 2MB
  // cnt, agg, degc contiguous -> single memset
  int*   cnt   = (int*)p;                   p += (size_t)E * 4;        // 512KB
  float* agg   = (float*)p;                 p += (size_t)N * 64 * 4;   // 4MB
  int*   degc  = (int*)p;                   p += (size_t)N * 4;        // 64KB
  unsigned short* Btr = (unsigned short*)p; p += 64 * 256 * 2;         // 32KB
  float* vs    = (float*)p;                 p += 512 * 4;              // 2KB

  hipMemsetAsync(cnt, 0,
                 (size_t)E * 4 + (size_t)N * 64 * 4 + (size_t)N * 4, stream);

  k_prevs<<<64, 256, 0, stream>>>(W, att_src, att_dst, Btr, vs);

  const int Mtot = M + E;
  const int ncast = E / 64;                  // 2048
  const int nfill = (Mtot + 1023) / 1024;    // 2176
  k_fused<<<ncast + nfill, 256, 0, stream>>>(
      x, vs, xb, a_src, a_dst, ei, M, E, cnt, csr, ncast, nfill);

  k_agg<<<E / 4, 256, 0, stream>>>(
      xb, (const float4*)a_src, (const float4*)a_dst, cnt, csr,
      rows, Btr, bias, agg, degc, E);

  k_final<<<(N + 3) / 4, 256, 0, stream>>>(agg, degc, wgt, wb, (float*)d_out, N);
}

// Round 9
// 298.659 us; speedup vs baseline: 1.1454x; 1.0022x over previous
//
#include <hip/hip_runtime.h>
#include <hip/hip_bf16.h>

// GAT on line graph. Pipeline (round 9):
//   k_prevs : vs[8][64] = W^T@att ; Btr[c][kap]=0.25*W[(kap>>6)*64+c][kap&63] bf16
//   k_fused : heterogeneous grid: cast blocks (x->bf16 xb + exact fp32
//             a_src/a_dst) paired with fill blocks (CSR bucket, 4 edges/thr).
//   k_agg   : per-dst wave softmax; alpha-weighted gather of x rows, SOFTWARE
//             PIPELINED 4-deep (batch n+1 loads in flight under batch n math);
//             half-wave reduce in-register, stage zl[4][260] conflict-free,
//             MFMA epilogue out = z @ Btr^T (+bias), atomic scatter.
//   k_final : scatter-mean normalize + 64x64 linear

#define CAP 64
#define ZST 260   // zl stride: mod32=4 -> 2-way max on epilogue reads (free)

using frag16 = __attribute__((ext_vector_type(8))) short;  // 8 bf16
using f32x4  = __attribute__((ext_vector_type(4))) float;
using f32x2  = __attribute__((ext_vector_type(2))) float;

__device__ __forceinline__ float wave_reduce_sum(float v) {
#pragma unroll
  for (int off = 32; off > 0; off >>= 1) v += __shfl_xor(v, off, 64);
  return v;
}

__device__ __forceinline__ unsigned short f2bf(float f) {
  union { float f; unsigned u; } v; v.f = f;
  return (unsigned short)((v.u + 0x8000u) >> 16);
}
__device__ __forceinline__ float bflo(unsigned u) {
  union { unsigned u; float f; } v; v.u = u << 16; return v.f;
}
__device__ __forceinline__ float bfhi(unsigned u) {
  union { unsigned u; float f; } v; v.u = u & 0xffff0000u; return v.f;
}
__device__ __forceinline__ unsigned pkbf(float lo, float hi) {
  union { __hip_bfloat162 b; unsigned u; } v;
  v.b = __float22bfloat162_rn(make_float2(lo, hi));   // v_cvt_pk_bf16_f32
  return v.u;
}

// ---------------- Pass 0: vs + Btr precompute ----------------
__global__ __launch_bounds__(256) void k_prevs(
    const float* __restrict__ W, const float* __restrict__ att_src,
    const float* __restrict__ att_dst, unsigned short* __restrict__ Btr,
    float* __restrict__ vs) {
  int t = blockIdx.x * 256 + threadIdx.x;    // 64 blocks -> 16384
  {
    int c = t >> 8, kap = t & 255;           // Btr[c][kap] = 0.25*W[h*64+c][k]
    int h = kap >> 6, k = kap & 63;
    Btr[t] = f2bf(0.25f * W[(size_t)(h * 64 + c) * 64 + k]);
  }
  if (blockIdx.x < 2) {
    int o = blockIdx.x * 256 + threadIdx.x;  // 0..511
    int j = o >> 6, c = o & 63;              // 0..3 src heads, 4..7 dst heads
    const float* att = (j < 4) ? att_src : att_dst;
    int hh = j & 3;
    float s = 0.f;
    for (int ch = 0; ch < 64; ++ch)
      s += W[(size_t)(hh * 64 + ch) * 64 + c] * att[hh * 64 + ch];
    vs[o] = s;
  }
}

// ---------------- Fused: cast blocks + fill blocks ----------------
__device__ __forceinline__ void cast_body(
    const float* __restrict__ x, const float* __restrict__ vs,
    unsigned short* __restrict__ xb, float* __restrict__ a_src,
    float* __restrict__ a_dst, int bid, float* vsl) {
  const int t = threadIdx.x;
  if (t < 128) ((float4*)vsl)[t] = ((const float4*)vs)[t];
  __syncthreads();
  const int w = t >> 6, lane = t & 63, l15 = lane & 15, l4 = lane >> 4;
  const int row = bid * 64 + w * 16 + l15;

  // lane's 16 dims: l4*16 .. +15
  const float4* xp = (const float4*)(x + (size_t)row * 64 + l4 * 16);
  float4 v0 = xp[0], v1 = xp[1], v2 = xp[2], v3 = xp[3];
  float xa[16] = {v0.x, v0.y, v0.z, v0.w, v1.x, v1.y, v1.z, v1.w,
                  v2.x, v2.y, v2.z, v2.w, v3.x, v3.y, v3.z, v3.w};

  // pack bf16 pairs (even dim = lo, odd = hi)
  uint2* dst = (uint2*)(xb + (size_t)row * 64 + l4 * 16);
  dst[0] = make_uint2(pkbf(xa[0], xa[1]),  pkbf(xa[2], xa[3]));
  dst[1] = make_uint2(pkbf(xa[4], xa[5]),  pkbf(xa[6], xa[7]));
  dst[2] = make_uint2(pkbf(xa[8], xa[9]),  pkbf(xa[10], xa[11]));
  dst[3] = make_uint2(pkbf(xa[12], xa[13]), pkbf(xa[14], xa[15]));

  // exact fp32 attention dots (partial over 16 dims, reduce across l4)
  float pj[8];
#pragma unroll
  for (int j = 0; j < 8; ++j) {
    const float4* q = (const float4*)(vsl + j * 64 + l4 * 16);
    float4 q0 = q[0], q1 = q[1], q2 = q[2], q3 = q[3];
    float s = xa[0] * q0.x + xa[1] * q0.y + xa[2] * q0.z + xa[3] * q0.w
            + xa[4] * q1.x + xa[5] * q1.y + xa[6] * q1.z + xa[7] * q1.w
            + xa[8] * q2.x + xa[9] * q2.y + xa[10] * q2.z + xa[11] * q2.w
            + xa[12] * q3.x + xa[13] * q3.y + xa[14] * q3.z + xa[15] * q3.w;
    s += __shfl_xor(s, 16, 64);
    s += __shfl_xor(s, 32, 64);
    pj[j] = s;
  }
  if (l4 == 0) {
    *(float4*)&a_src[(size_t)row * 4] = make_float4(pj[0], pj[1], pj[2], pj[3]);
    *(float4*)&a_dst[(size_t)row * 4] = make_float4(pj[4], pj[5], pj[6], pj[7]);
  }
}

__device__ __forceinline__ void fill_body(
    const int* __restrict__ ei, int M, int E,
    int* __restrict__ cnt, int* __restrict__ csr, int bid) {
  const int Mtot = M + E;
  const int base = bid * 1024 + threadIdx.x;
  int mm[4], ss[4], dd[4];
#pragma unroll
  for (int i = 0; i < 4; ++i) {
    int m = base + i * 256;
    mm[i] = m;
    if (m < Mtot) {
      if (m < M) { ss[i] = ei[m]; dd[i] = ei[M + m]; }
      else       { ss[i] = m - M; dd[i] = m - M; }   // self loop
    }
  }
  int pos[4];
#pragma unroll
  for (int i = 0; i < 4; ++i)
    if (mm[i] < Mtot) pos[i] = atomicAdd(&cnt[dd[i]], 1);
#pragma unroll
  for (int i = 0; i < 4; ++i)
    if (mm[i] < Mtot && pos[i] < CAP) csr[(size_t)dd[i] * CAP + pos[i]] = ss[i];
}

__global__ __launch_bounds__(256, 4) void k_fused(
    const float* __restrict__ x, const float* __restrict__ vs,
    unsigned short* __restrict__ xb,
    float* __restrict__ a_src, float* __restrict__ a_dst,
    const int* __restrict__ ei, int M, int E,
    int* __restrict__ cnt, int* __restrict__ csr,
    int ncast, int nfill) {
  __shared__ float vsl[512];
  const int bid = blockIdx.x;
  int npair = 2 * min(ncast, nfill);
  if (bid < npair) {
    if (bid & 1) cast_body(x, vs, xb, a_src, a_dst, bid >> 1, vsl);
    else         fill_body(ei, M, E, cnt, csr, bid >> 1);
  } else {
    int r = bid - npair;
    if (nfill > ncast) fill_body(ei, M, E, cnt, csr, ncast + r);
    else               cast_body(x, vs, xb, a_src, a_dst, ncast + r, vsl);
  }
}

// ---------------- Aggregation: softmax + pipelined x-gather + MFMA ---------
__global__ __launch_bounds__(256) void k_agg(
    const unsigned short* __restrict__ xb, const float4* __restrict__ a_src,
    const float4* __restrict__ a_dst, const int* __restrict__ cnt,
    const int* __restrict__ csr, const int* __restrict__ rows,
    const unsigned short* __restrict__ Btr, const float* __restrict__ bias,
    float* __restrict__ agg, int* __restrict__ degc, int E) {
  __shared__ float4 alds[4 * 64];
  __shared__ int    olds[4 * 64];        // pre-scaled byte offsets: src*128
  __shared__ float  zl[4 * ZST];         // [dst wave][kappa], stride 260
  const int w = threadIdx.x >> 6, lane = threadIdx.x & 63;
  const int e = blockIdx.x * 4 + w;      // grid exactly E/4

  int deg = cnt[e];
  if (deg > CAP) deg = CAP;
  float4 ad = a_dst[e];

  int src = 0;
  float ex0 = 0.f, ex1 = 0.f, ex2 = 0.f, ex3 = 0.f;
  if (lane < deg) {
    src = csr[(size_t)e * CAP + lane];
    float4 as = a_src[src];
    float l0 = as.x + ad.x; l0 = l0 > 0.f ? l0 : 0.2f * l0;
    float l1 = as.y + ad.y; l1 = l1 > 0.f ? l1 : 0.2f * l1;
    float l2 = as.z + ad.z; l2 = l2 > 0.f ? l2 : 0.2f * l2;
    float l3 = as.w + ad.w; l3 = l3 > 0.f ? l3 : 0.2f * l3;
    ex0 = __expf(l0); ex1 = __expf(l1); ex2 = __expf(l2); ex3 = __expf(l3);
  }
  float i0 = 1.f / (wave_reduce_sum(ex0) + 1e-16f);
  float i1 = 1.f / (wave_reduce_sum(ex1) + 1e-16f);
  float i2 = 1.f / (wave_reduce_sum(ex2) + 1e-16f);
  float i3 = 1.f / (wave_reduce_sum(ex3) + 1e-16f);

  alds[w * 64 + lane] = make_float4(ex0 * i0, ex1 * i1, ex2 * i2, ex3 * i3);
  olds[w * 64 + lane] = src << 7;        // x row = 128 bytes
  __syncthreads();

  // phase 2: packed z accumulation, SOFTWARE-PIPELINED 4-deep.
  // half-wave j handles neighbors k = 2i+j; lane (j,d2) covers dims 2d2,2d2+1.
  const int j = lane >> 5, d2 = lane & 31;
  const char* xbase = (const char*)xb + d2 * 4;
  const int kb = w * 64 + j;
  f32x2 zz0 = {0.f, 0.f}, zz1 = {0.f, 0.f}, zz2 = {0.f, 0.f}, zz3 = {0.f, 0.f};
  const int npair_ = (deg + 1) >> 1;

#define GLD(I) (*(const unsigned*)(xbase + (size_t)(unsigned)olds[kb + 2 * (I)]))
#define ALD(I) alds[kb + 2 * (I)]
#define CONS(A_, V_) { \
    f32x2 xv; xv.x = bflo(V_); xv.y = bfhi(V_); \
    f32x2 c0 = {(A_).x, (A_).x}, c1 = {(A_).y, (A_).y}; \
    f32x2 c2 = {(A_).z, (A_).z}, c3 = {(A_).w, (A_).w}; \
    zz0 += c0 * xv; zz1 += c1 * xv; zz2 += c2 * xv; zz3 += c3 * xv; }

  int i = 0;
  if (npair_ >= 4) {
    unsigned v0 = GLD(0), v1 = GLD(1), v2 = GLD(2), v3 = GLD(3);
    float4  A0 = ALD(0), A1 = ALD(1), A2 = ALD(2), A3 = ALD(3);
    for (; i + 8 <= npair_; i += 4) {
      unsigned n0 = GLD(i + 4), n1 = GLD(i + 5);
      unsigned n2 = GLD(i + 6), n3 = GLD(i + 7);
      float4  B0 = ALD(i + 4), B1 = ALD(i + 5);
      float4  B2 = ALD(i + 6), B3 = ALD(i + 7);
      CONS(A0, v0) CONS(A1, v1) CONS(A2, v2) CONS(A3, v3)
      v0 = n0; v1 = n1; v2 = n2; v3 = n3;
      A0 = B0; A1 = B1; A2 = B2; A3 = B3;
    }
    CONS(A0, v0) CONS(A1, v1) CONS(A2, v2) CONS(A3, v3)
    i += 4;
  }
  for (; i < npair_; ++i) {
    unsigned v = GLD(i);
    float4 A = ALD(i);
    CONS(A, v)
  }
#undef GLD
#undef ALD
#undef CONS

  // reduce the two parity halves in-register
  zz0.x += __shfl_xor(zz0.x, 32, 64); zz0.y += __shfl_xor(zz0.y, 32, 64);
  zz1.x += __shfl_xor(zz1.x, 32, 64); zz1.y += __shfl_xor(zz1.y, 32, 64);
  zz2.x += __shfl_xor(zz2.x, 32, 64); zz2.y += __shfl_xor(zz2.y, 32, 64);
  zz3.x += __shfl_xor(zz3.x, 32, 64); zz3.y += __shfl_xor(zz3.y, 32, 64);

  // phase 3: stage z (j==0 half only; both halves identical now)
  if (j == 0) {
    float* zw = &zl[w * ZST + 2 * d2];
    *(float2*)&zw[0 * 64] = make_float2(zz0.x, zz0.y);
    *(float2*)&zw[1 * 64] = make_float2(zz1.x, zz1.y);
    *(float2*)&zw[2 * 64] = make_float2(zz2.x, zz2.y);
    *(float2*)&zw[3 * 64] = make_float2(zz3.x, zz3.y);
  }
  __syncthreads();

  // epilogue: out[4 dst][64 c] = z @ Btr^T ; wave w -> col tile w (c=w*16+l15)
  const int l15 = lane & 15, l4 = lane >> 4;
  const int drow = l15 & 3;              // A row content: dst index (dups ok)
  const unsigned short* bp = Btr + (size_t)(w * 16 + l15) * 256 + l4 * 8;
  const float* zp = &zl[drow * ZST + l4 * 8];
  f32x4 acc = {0.f, 0.f, 0.f, 0.f};
#pragma unroll
  for (int kk = 0; kk < 8; ++kk) {
    const float4* z4p = (const float4*)(zp + kk * 32);
    float4 za = z4p[0], zb = z4p[1];
    frag16 af;
    unsigned* au = (unsigned*)&af;
    au[0] = pkbf(za.x, za.y);
    au[1] = pkbf(za.z, za.w);
    au[2] = pkbf(zb.x, zb.y);
    au[3] = pkbf(zb.z, zb.w);
    frag16 bfg = *(const frag16*)(bp + kk * 32);
    acc = __builtin_amdgcn_mfma_f32_16x16x32_bf16(af, bfg, acc, 0, 0, 0);
  }
  // C map: row = l4*4 + reg, col = l15 -> rows 0..3 live in lanes l4==0
  if (l4 == 0) {
    int ccol = w * 16 + l15;
    float bs = bias[ccol];
#pragma unroll
    for (int r = 0; r < 4; ++r) {
      int ee = blockIdx.x * 4 + r;
      atomicAdd(&agg[(size_t)rows[ee] * 64 + ccol], acc[r] + bs);
    }
  }
  if (lane == 0) atomicAdd(&degc[rows[e]], 1);
}

// ---------------- scatter-mean normalize + final linear ----------------
__global__ __launch_bounds__(256) void k_final(
    const float* __restrict__ agg, const int* __restrict__ degc,
    const float* __restrict__ wgt, const float* __restrict__ wb,
    float* __restrict__ out, int N) {
  __shared__ float wtt[64 * 65];
  const int t = threadIdx.x;
#pragma unroll
  for (int i = 0; i < 16; ++i) {
    int idx = t + i * 256;                       // idx = c*64 + k
    wtt[(idx & 63) * 65 + (idx >> 6)] = wgt[idx];
  }
  __syncthreads();
  const int w = t >> 6, lane = t & 63;
  int n = blockIdx.x * 4 + w;
  if (n >= N) return;
  int dg = degc[n];
  float av = dg > 0 ? agg[(size_t)n * 64 + lane] / (float)dg : 0.f;
  float o = 0.f;
#pragma unroll
  for (int k = 0; k < 64; ++k) {
    o += __shfl(av, k, 64) * wtt[k * 65 + lane];
  }
  out[(size_t)n * 64 + lane] = o + wb[lane];
}

extern "C" void kernel_launch(void* const* d_in, const int* in_sizes, int n_in,
                              void* d_out, int out_size, void* d_ws, size_t ws_size,
                              hipStream_t stream) {
  const float* x       = (const float*)d_in[0];
  const int*   ei      = (const int*)d_in[1];
  const int*   rows    = (const int*)d_in[2];
  const float* W       = (const float*)d_in[3];
  const float* att_src = (const float*)d_in[4];
  const float* att_dst = (const float*)d_in[5];
  const float* bias    = (const float*)d_in[6];
  const float* wgt     = (const float*)d_in[7];
  const float* wb      = (const float*)d_in[8];

  const int E = in_sizes[0] / 64;     // 131072
  const int M = in_sizes[1] / 2;      // 2097152
  const int N = out_size / 64;        // 16384

  char* p = (char*)d_ws;
  unsigned short* xb = (unsigned short*)p;  p += (size_t)E * 64 * 2;   // 16MB
  int*   csr   = (int*)p;                   p += (size_t)E * CAP * 4;  // 32MB
  float* a_src = (float*)p;                 p += (size_t)E * 4 * 4;    // 2MB
  float* a_dst = (float*)p;                 p += (size_t)E * 4 * 4;    // 2MB
  // cnt, agg, degc contiguous -> single memset
  int*   cnt   = (int*)p;                   p += (size_t)E * 4;        // 512KB
  float* agg   = (float*)p;                 p += (size_t)N * 64 * 4;   // 4MB
  int*   degc  = (int*)p;                   p += (size_t)N * 4;        // 64KB
  unsigned short* Btr = (unsigned short*)p; p += 64 * 256 * 2;         // 32KB
  float* vs    = (float*)p;                 p += 512 * 4;              // 2KB

  hipMemsetAsync(cnt, 0,
                 (size_t)E * 4 + (size_t)N * 64 * 4 + (size_t)N * 4, stream);

  k_prevs<<<64, 256, 0, stream>>>(W, att_src, att_dst, Btr, vs);

  const int Mtot = M + E;
  const int ncast = E / 64;                  // 2048
  const int nfill = (Mtot + 1023) / 1024;    // 2176
  k_fused<<<ncast + nfill, 256, 0, stream>>>(
      x, vs, xb, a_src, a_dst, ei, M, E, cnt, csr, ncast, nfill);

  k_agg<<<E / 4, 256, 0, stream>>>(
      xb, (const float4*)a_src, (const float4*)a_dst, cnt, csr,
      rows, Btr, bias, agg, degc, E);

  k_final<<<(N + 3) / 4, 256, 0, stream>>>(agg, degc, wgt, wb, (float*)d_out, N);
}